// Round 1
// baseline (3343.962 us; speedup 1.0000x reference)
//
#include <hip/hip_runtime.h>
#include <stdint.h>

typedef uint32_t u32;
typedef uint64_t u64;

#define VN 50000
#define FN 100000
#define K3F 300000
#define EMAX 300000
#define NEDG 900000
#define NB1 1172          // ceil(300000/256)
#define NB2 3516          // ceil(900000/256)
#define NBC 98            // ceil(100000/1024)
#define PADKEY 0x00FFFFFFu

// ---------------- workspace layout (u32 units) ----------------
#define W_A      0u        // 300000  (biased keys / sorted keys)   [overlaid by DSTA later]
#define W_B      300000u   // 300000  ping buffer
#define W_FLAGS  600000u
#define W_RANKU  900000u
#define W_UKEYS  1200000u
#define W_DSTA   0u        // 900000  edge-list dst (overlays A/B/FLAGS)
#define W_SRCA   900000u   // 900000  (overlays RANKU/UKEYS/pad)
#define W_DSTB   1800000u
#define W_SRCB   2700000u
#define W_FEID   3600000u  // 300000
#define W_ENIDX  3900000u  // 600000
#define W_XE     4500000u  // 900000 f32
#define W_OFF    5400000u  // 300001
#define W_AGGXE  5700004u  // 900000 f32
#define W_P      6600004u  // 600000 f32
#define W_Q      7200004u  // 600000 f32
#define W_Y      7800004u  // 300000 f32
#define W_YMAP   8100004u
#define W_TFLAG  8400004u
#define W_TIER   8700004u
#define W_SEL    9000004u
#define W_SELR   9300004u
#define W_CAT    9600004u  // 100000
#define W_CATR   9700004u  // 100000
#define W_NFI    9800004u  // 1200000 int (new faces)
#define W_HIST   11000004u // 900096
#define W_SUMS   11900100u // 4096
#define W_CATH   11904196u // 1024
#define W_SCAL   11905220u // 64

#define S_E 0
#define S_NUM 1
#define S_PFX 2
#define S_KREM 3
#define S_TU 4
#define S_R 5
#define S_NF 6
#define S_NEN 7
#define S_O1 8
#define S_O2 9
#define S_O3 10
#define S_RS 16
#define S_GS 24
#define S_GP 32

// ---------------- threefry2x32, key = (0, 42) ----------------
__device__ __forceinline__ void tf2x32(u32 x0, u32 x1, u32& o0, u32& o1) {
  const u32 ks0 = 0u, ks1 = 42u, ks2 = 0x1BD11BDAu ^ 0u ^ 42u;
  x0 += ks0; x1 += ks1;
#define TFR(r) { x0 += x1; x1 = (x1<<(r))|(x1>>(32-(r))); x1 ^= x0; }
  TFR(13) TFR(15) TFR(26) TFR(6)   x0 += ks1; x1 += ks2 + 1u;
  TFR(17) TFR(29) TFR(16) TFR(24)  x0 += ks2; x1 += ks0 + 2u;
  TFR(13) TFR(15) TFR(26) TFR(6)   x0 += ks0; x1 += ks1 + 3u;
  TFR(17) TFR(29) TFR(16) TFR(24)  x0 += ks1; x1 += ks2 + 4u;
  TFR(13) TFR(15) TFR(26) TFR(6)   x0 += ks2; x1 += ks0 + 5u;
#undef TFR
  o0 = x0; o1 = x1;
}

// ---------------- generic exclusive scan (u32) ----------------
__global__ void scan_blocks(const u32* __restrict__ in, u32* __restrict__ out,
                            u32* __restrict__ sums, int n) {
  __shared__ u32 lds[256];
  int t = threadIdx.x;
  int base = blockIdx.x*1024 + t*4;
  u32 v[4]; u32 tot = 0;
  for (int k = 0; k < 4; ++k) { v[k] = (base+k < n) ? in[base+k] : 0u; tot += v[k]; }
  lds[t] = tot; __syncthreads();
  for (int o = 1; o < 256; o <<= 1) {
    u32 x = (t >= o) ? lds[t-o] : 0u; __syncthreads();
    lds[t] += x; __syncthreads();
  }
  u32 excl = lds[t] - tot;
  if (t == 255) sums[blockIdx.x] = lds[255];
  u32 run = excl;
  for (int k = 0; k < 4; ++k) { if (base+k < n) out[base+k] = run; run += v[k]; }
}

__global__ void scan_sums(u32* __restrict__ s, int nb) {
  __shared__ u32 lds[256];
  __shared__ u32 carry;
  int t = threadIdx.x;
  if (t == 0) carry = 0;
  __syncthreads();
  for (int base = 0; base < nb; base += 1024) {
    int idx = base + t*4;
    u32 v[4]; u32 tot = 0;
    for (int k = 0; k < 4; ++k) { v[k] = (idx+k < nb) ? s[idx+k] : 0u; tot += v[k]; }
    lds[t] = tot; __syncthreads();
    for (int o = 1; o < 256; o <<= 1) {
      u32 x = (t >= o) ? lds[t-o] : 0u; __syncthreads();
      lds[t] += x; __syncthreads();
    }
    u32 excl = lds[t] - tot;
    u32 ctot = lds[255];
    u32 c = carry;
    __syncthreads();
    u32 run = c + excl;
    for (int k = 0; k < 4; ++k) { if (idx+k < nb) s[idx+k] = run; run += v[k]; }
    if (t == 0) carry = c + ctot;
    __syncthreads();
  }
}

__global__ void scan_add(u32* __restrict__ out, const u32* __restrict__ sums, int n) {
  int base = blockIdx.x*1024 + threadIdx.x*4;
  u32 a = sums[blockIdx.x];
  for (int k = 0; k < 4; ++k) if (base+k < n) out[base+k] += a;
}

// ---------------- radix sort (8-bit LSD, stable) ----------------
__global__ void k_rhist(const u32* __restrict__ keys, u32* __restrict__ hist,
                        int n, int shift, int nb) {
  __shared__ u32 h[256];
  int t = threadIdx.x;
  h[t] = 0; __syncthreads();
  int i = blockIdx.x*256 + t;
  if (i < n) atomicAdd(&h[(keys[i]>>shift)&255u], 1u);
  __syncthreads();
  hist[(u32)t*nb + blockIdx.x] = h[t];
}

__global__ void k_rscat(const u32* __restrict__ keys, const u32* __restrict__ pay,
                        u32* __restrict__ okeys, u32* __restrict__ opay,
                        const u32* __restrict__ hist, int n, int shift, int nb, int haspay) {
  __shared__ u64 ball[4][8];
  __shared__ u64 vmask[4];
  int t = threadIdx.x, w = t>>6, lane = t&63;
  int i = blockIdx.x*256 + t;
  bool valid = i < n;
  u32 k = valid ? keys[i] : 0u;
  u32 d = (k>>shift)&255u;
  for (int bit = 0; bit < 8; ++bit) {
    u64 bm = __ballot(valid && ((d>>bit)&1u));
    if (lane == 0) ball[w][bit] = bm;
  }
  u64 vb = __ballot(valid ? 1 : 0);
  if (lane == 0) vmask[w] = vb;
  __syncthreads();
  if (valid) {
    u32 rank = 0;
    for (int ww = 0; ww < w; ++ww) {
      u64 m = vmask[ww];
      for (int bit = 0; bit < 8; ++bit) { u64 bb = ball[ww][bit]; m &= ((d>>bit)&1u) ? bb : ~bb; }
      rank += (u32)__popcll(m);
    }
    u64 m = vmask[w];
    for (int bit = 0; bit < 8; ++bit) { u64 bb = ball[w][bit]; m &= ((d>>bit)&1u) ? bb : ~bb; }
    rank += (u32)__popcll(m & ((1ull<<lane)-1ull));
    u32 pos = hist[d*(u32)nb + blockIdx.x] + rank;
    okeys[pos] = k;
    if (haspay) opay[pos] = pay[i];
  }
}

// ---------------- pipeline kernels ----------------
__global__ void k_keys(const int* __restrict__ face, u32* __restrict__ keys) {
  int i = blockIdx.x*256 + threadIdx.x;
  if (i >= K3F) return;
  int s = i / FN, f = i - s*FN;
  int v0 = face[f*3 + s];
  int v1 = face[f*3 + (s == 2 ? 0 : s+1)];
  int a = min(v0, v1), b = max(v0, v1);
  u32 key = (u32)a * (u32)VN + (u32)b;   // int32 wraparound, matches jnp
  keys[i] = key ^ 0x80000000u;           // biased: unsigned order == signed order
}

__global__ void k_uflag(const u32* __restrict__ sk, u32* __restrict__ flags) {
  int i = blockIdx.x*256 + threadIdx.x;
  if (i >= K3F) return;
  flags[i] = (i == 0 || sk[i] != sk[i-1]) ? 1u : 0u;
}

__global__ void k_uwrite(const u32* __restrict__ sk, const u32* __restrict__ flags,
                         const u32* __restrict__ rank, u32* __restrict__ ukeys,
                         u32* __restrict__ scal, const int* __restrict__ divp) {
  int i = blockIdx.x*256 + threadIdx.x;
  if (i >= K3F) return;
  if (flags[i]) ukeys[rank[i]] = sk[i];
  if (i == K3F-1) { u32 E = rank[i] + flags[i]; scal[S_E] = E; scal[S_NUM] = E / (u32)divp[0]; }
}

__global__ void k_ennode(const u32* __restrict__ ukeys, const u32* __restrict__ scal,
                         u32* __restrict__ enidx, float* __restrict__ dout) {
  int e = blockIdx.x*256 + threadIdx.x;
  if (e >= (int)scal[S_E]) return;
  int k = (int)(ukeys[e] ^ 0x80000000u);
  long long kk = (long long)k;
  long long qq = (kk - (kk < 0 ? (long long)(VN-1) : 0ll)) / VN; // floor div
  int q = (int)qq;
  int r = (int)(kk - qq * VN);
  dout[2*e]   = (float)q;
  dout[2*e+1] = (float)r;
  enidx[2*e]   = (u32)(q < 0 ? q + VN : q);  // numpy-style negative index wrap
  enidx[2*e+1] = (u32)r;
}

__global__ void k_feid(const int* __restrict__ face, const u32* __restrict__ ukeys,
                       const u32* __restrict__ scal, u32* __restrict__ feid) {
  int i = blockIdx.x*256 + threadIdx.x;
  if (i >= K3F) return;
  int s = i / FN, f = i - s*FN;
  int v0 = face[f*3 + s];
  int v1 = face[f*3 + (s == 2 ? 0 : s+1)];
  int a = min(v0, v1), b = max(v0, v1);
  u32 kb = ((u32)a * (u32)VN + (u32)b) ^ 0x80000000u;
  u32 lo = 0, hi = scal[S_E];
  while (lo < hi) { u32 mid = (lo+hi)>>1; if (ukeys[mid] < kb) lo = mid+1; else hi = mid; }
  feid[f*3 + s] = lo;
}

__global__ void k_xe(const float* __restrict__ x, const u32* __restrict__ enidx,
                     const u32* __restrict__ scal, float* __restrict__ xe) {
  int e = blockIdx.x*256 + threadIdx.x;
  if (e >= (int)scal[S_E]) return;
  u32 i0 = enidx[2*e], i1 = enidx[2*e+1];
  for (int c = 0; c < 3; ++c) xe[e*3+c] = 0.5f*(x[i0*3+c] + x[i1*3+c]);
}

__global__ void k_elist(const u32* __restrict__ feid, const u32* __restrict__ scal,
                        u32* __restrict__ dst, u32* __restrict__ src) {
  int i = blockIdx.x*256 + threadIdx.x;
  if (i >= NEDG) return;
  const int sb[6] = {0,1,1,2,2,0};
  const int db[6] = {1,0,2,1,0,2};
  if (i < 6*FN) {
    int b = i / FN, f = i - b*FN;
    src[i] = feid[f*3 + sb[b]];
    dst[i] = feid[f*3 + db[b]];
  } else {
    int e = i - 6*FN;
    if (e < (int)scal[S_E]) { src[i] = (u32)e; dst[i] = (u32)e; }
    else { src[i] = 0u; dst[i] = PADKEY; }
  }
}

__global__ void k_off(const u32* __restrict__ dsts, const u32* __restrict__ scal,
                      u32* __restrict__ off) {
  int e = blockIdx.x*256 + threadIdx.x;
  if (e > (int)scal[S_E]) return;
  u32 key = (u32)e, lo = 0, hi = NEDG;
  while (lo < hi) { u32 mid = (lo+hi)>>1; if (dsts[mid] < key) lo = mid+1; else hi = mid; }
  off[e] = lo;
}

__global__ void k_aggxe(const u32* __restrict__ off, const u32* __restrict__ srcs,
                        const float* __restrict__ xe, const u32* __restrict__ scal,
                        float* __restrict__ agg) {
  int e = blockIdx.x*256 + threadIdx.x;
  if (e >= (int)scal[S_E]) return;
  u32 s = off[e], t = off[e+1];
  float c0 = 0.f, c1 = 0.f, c2 = 0.f;
  for (u32 j = s; j < t; ++j) {               // sequential in original edge order (stable sort)
    u32 u = srcs[j];
    c0 += xe[u*3]; c1 += xe[u*3+1]; c2 += xe[u*3+2];
  }
  agg[e*3] = c0; agg[e*3+1] = c1; agg[e*3+2] = c2;
}

// fused layer1(relu-gsnconv) + projection to W2s/W2n — one wave per edge-node
__global__ void k_l12(const float* __restrict__ xe, const float* __restrict__ agg,
                      const u32* __restrict__ off, const u32* __restrict__ scal,
                      const float* __restrict__ W1s, const float* __restrict__ W1n,
                      const float* __restrict__ b1,
                      const float* __restrict__ W2s, const float* __restrict__ W2n,
                      float* __restrict__ P, float* __restrict__ Q) {
  int w = threadIdx.x >> 6, lane = threadIdx.x & 63;
  int e = blockIdx.x*4 + w;
  if (e >= (int)scal[S_E]) return;
  float x0 = xe[e*3], x1 = xe[e*3+1], x2 = xe[e*3+2];
  float dg = (float)(off[e+1] - off[e]);
  float m0 = agg[e*3]/dg, m1 = agg[e*3+1]/dg, m2 = agg[e*3+2]/dg;
  float p0 = 0.f, p1 = 0.f, q0 = 0.f, q1 = 0.f;
  for (int kk = 0; kk < 4; ++kk) {
    int hid = lane + 64*kk;
    float s1 = x0*W1s[hid] + x1*W1s[256+hid] + x2*W1s[512+hid];
    float s2 = m0*W1n[hid] + m1*W1n[256+hid] + m2*W1n[512+hid];
    float h = fmaxf(s1 + s2 + b1[hid], 0.0f);
    p0 += h*W2s[hid*2];  p1 += h*W2s[hid*2+1];
    q0 += h*W2n[hid*2];  q1 += h*W2n[hid*2+1];
  }
  for (int o = 32; o; o >>= 1) {
    p0 += __shfl_xor(p0, o); p1 += __shfl_xor(p1, o);
    q0 += __shfl_xor(q0, o); q1 += __shfl_xor(q1, o);
  }
  if (lane == 0) { P[2*e] = p0; P[2*e+1] = p1; Q[2*e] = q0; Q[2*e+1] = q1; }
}

__global__ void k_scores(const float* __restrict__ P, const float* __restrict__ Q,
                         const u32* __restrict__ off, const u32* __restrict__ srcs,
                         const float* __restrict__ b2, const u32* __restrict__ scal,
                         float* __restrict__ Y, u32* __restrict__ ymap) {
  int e = blockIdx.x*256 + threadIdx.x;
  u32 E = scal[S_E];
  if (e >= (int)E) return;
  u32 s = off[e], t = off[e+1];
  float dg = (float)(t - s);
  float a0 = 0.f, a1 = 0.f;
  for (u32 j = s; j < t; ++j) { u32 u = srcs[j]; a0 += Q[2*u]; a1 += Q[2*u+1]; }
  float z0 = P[2*e]   + a0/dg + b2[0];
  float z1 = P[2*e+1] + a1/dg + b2[1];
  float l0 = 1.0f/(1.0f + expf(-z0));
  float l1 = 1.0f/(1.0f + expf(-z1));
  // JAX partitionable threefry: bits(i) = o0^o1 of threefry(key=(0,42), counts=(i>>32, i&...))
  u32 g0b, g1b;
  { u32 o0,o1; tf2x32(0u, 2u*(u32)e,      o0, o1); g0b = o0 ^ o1; }
  { u32 o0,o1; tf2x32(0u, 2u*(u32)e + 1u, o0, o1); g1b = o0 ^ o1; }
  float U0 = __uint_as_float((g0b>>9) | 0x3f800000u) - 1.0f;
  float U1 = __uint_as_float((g1b>>9) | 0x3f800000u) - 1.0f;
  float g0 = -logf(-logf(U0 + 1e-20f) + 1e-20f);
  float g1 = -logf(-logf(U1 + 1e-20f) + 1e-20f);
  float A0 = (l0 + g0)/0.1f;
  float A1 = (l1 + g1)/0.1f;
  float mx = fmaxf(A0, A1);
  float e0 = expf(A0-mx), e1 = expf(A1-mx);
  float y = e0/(e0+e1);
  Y[e] = y;
  ymap[e] = __float_as_uint(y) | 0x80000000u;   // monotone map (y >= 0)
}

// ---------------- exact top-k threshold (byte-wise descent) ----------------
__global__ void k_tkinit(u32* __restrict__ scal, u32* __restrict__ hist) {
  int t = threadIdx.x;
  if (t < 256) hist[t] = 0u;
  if (t == 0) { scal[S_PFX] = 0u; scal[S_KREM] = scal[S_NUM]; }
}

__global__ void k_tkhist(const u32* __restrict__ ymap, const u32* __restrict__ scal,
                         u32* __restrict__ hist, int byte) {
  int e = blockIdx.x*256 + threadIdx.x;
  if (e >= (int)scal[S_E]) return;
  u32 u = ymap[e];
  bool match = (byte == 3) || ((u >> ((byte+1)*8)) == scal[S_PFX]);
  if (match) atomicAdd(&hist[(u >> (byte*8)) & 255u], 1u);
}

__global__ void k_tksel(u32* __restrict__ scal, u32* __restrict__ hist, int byte) {
  if (threadIdx.x != 0 || blockIdx.x != 0) return;
  u32 krem = scal[S_KREM], pfx = scal[S_PFX];
  u32 chosen = 0;
  for (int b = 255; b >= 0; --b) {
    u32 c = hist[b];
    if (krem <= c) { chosen = (u32)b; break; }
    krem -= c;
  }
  pfx = (pfx << 8) | chosen;
  scal[S_PFX] = pfx; scal[S_KREM] = krem;
  if (byte == 0) { scal[S_TU] = pfx; scal[S_R] = krem; }
  for (int i = 0; i < 256; ++i) hist[i] = 0u;
}

__global__ void k_tflag(const u32* __restrict__ ymap, const u32* __restrict__ scal,
                        u32* __restrict__ tf) {
  int e = blockIdx.x*256 + threadIdx.x;
  if (e >= EMAX) return;
  tf[e] = (e < (int)scal[S_E] && ymap[e] == scal[S_TU]) ? 1u : 0u;
}

__global__ void k_sel(const u32* __restrict__ ymap, const u32* __restrict__ tier,
                      const u32* __restrict__ scal, u32* __restrict__ sel) {
  int e = blockIdx.x*256 + threadIdx.x;
  if (e >= EMAX) return;
  u32 v = 0;
  if (e < (int)scal[S_E]) {
    u32 u = ymap[e];
    v = (u > scal[S_TU]) || (u == scal[S_TU] && tier[e] < scal[S_R]);
  }
  sel[e] = v ? 1u : 0u;
}

// ---------------- mesh collapse ----------------
__global__ void k_cat(const u32* __restrict__ feid, const u32* __restrict__ sel,
                      u32* __restrict__ cat) {
  int f = blockIdx.x*256 + threadIdx.x;
  if (f >= FN) return;
  u32 m0 = sel[feid[f*3]], m1 = sel[feid[f*3+1]], m2 = sel[feid[f*3+2]];
  u32 pen = m0 + m1 + m2;
  u32 psi = m1 + 2u*m2;
  u32 c = (pen == 0) ? 0u : (pen == 1) ? (1u+psi) : (pen == 2) ? (3u+psi) : 7u;
  cat[f] = c;
}

__global__ void k_cathist(const u32* __restrict__ cat, u32* __restrict__ ch) {
  __shared__ u32 h[8];
  int t = threadIdx.x;
  if (t < 8) h[t] = 0u;
  __syncthreads();
  int base = blockIdx.x*1024 + t*4;
  for (int k = 0; k < 4; ++k) if (base+k < FN) atomicAdd(&h[cat[base+k]], 1u);
  __syncthreads();
  if (t < 8) ch[(u32)t*NBC + blockIdx.x] = h[t];
}

__global__ void k_catoff(u32* __restrict__ ch, u32* __restrict__ scal) {
  if (threadIdx.x || blockIdx.x) return;
  u32 tot[8];
  for (int c = 0; c < 8; ++c) { u32 s = 0; for (int b = 0; b < NBC; ++b) s += ch[c*NBC+b]; tot[c] = s; }
  u32 run = 0;
  for (int i = 0; i < 8*NBC; ++i) { u32 v = ch[i]; ch[i] = run; run += v; }
  u32 n0 = tot[0], n1 = tot[1]+tot[2]+tot[3], n2 = tot[4]+tot[5]+tot[6], n3 = tot[7];
  u32 NF = n0 + 2u*n1 + 3u*n2 + 4u*n3;
  u32 E = scal[S_E], num = scal[S_NUM];
  u32 NEn = (u32)VN + num + 3u*NF;
  scal[S_NF] = NF; scal[S_NEN] = NEn;
  scal[S_O1] = 2u*E;
  scal[S_O2] = 2u*E + 3u*NF;
  scal[S_O3] = 2u*E + 3u*NF + 2u*NEn;
  u32 RS[8] = {0u, n0,n0,n0, n0+2u*n1, n0+2u*n1, n0+2u*n1, n0+2u*n1+3u*n2};
  u32 GS[8] = {0u, n1,n1,n1, n2,n2,n2, n3};
  u32 GP[8] = {0u, n0,n0,n0, n0+n1, n0+n1, n0+n1, n0+n1+n2};
  for (int i = 0; i < 8; ++i) { scal[S_RS+i] = RS[i]; scal[S_GS+i] = GS[i]; scal[S_GP+i] = GP[i]; }
}

__global__ void k_catrank(const u32* __restrict__ cat, const u32* __restrict__ ch,
                          u32* __restrict__ cr) {
  __shared__ u32 lds[256];
  int t = threadIdx.x;
  int base = blockIdx.x*1024 + t*4;
  u32 cc[4], loc[4];
  u32 cnt[8] = {0,0,0,0,0,0,0,0};
  for (int k = 0; k < 4; ++k) {
    int i = base + k;
    if (i < FN) { u32 c = cat[i]; cc[k] = c; loc[k] = cnt[c]++; }
    else cc[k] = 8u;
  }
  u32 tb[8];
  for (int c = 0; c < 8; ++c) {
    lds[t] = cnt[c]; __syncthreads();
    for (int o = 1; o < 256; o <<= 1) {
      u32 x = (t >= o) ? lds[t-o] : 0u; __syncthreads();
      lds[t] += x; __syncthreads();
    }
    tb[c] = lds[t] - cnt[c];
    __syncthreads();
  }
  for (int k = 0; k < 4; ++k) {
    int i = base + k;
    if (i < FN) { u32 c = cc[k]; cr[i] = ch[c*NBC + blockIdx.x] + tb[c] + loc[k]; }
  }
}

__global__ void k_wfaces(const int* __restrict__ face, const u32* __restrict__ cat,
                         const u32* __restrict__ cr, const u32* __restrict__ feid,
                         const u32* __restrict__ selr, const u32* __restrict__ scal,
                         int* __restrict__ nfi, float* __restrict__ dout) {
  int f = blockIdx.x*256 + threadIdx.x;
  if (f >= FN) return;
  const int nfc[8] = {1,2,2,2,3,3,3,4};
  const int tri[8][4][3] = {
    {{0,2,4},{0,0,0},{0,0,0},{0,0,0}},
    {{0,1,4},{1,2,4},{0,0,0},{0,0,0}},
    {{2,3,0},{3,4,0},{0,0,0},{0,0,0}},
    {{4,5,2},{5,0,2},{0,0,0},{0,0,0}},
    {{0,1,4},{1,2,3},{1,3,4},{0,0,0}},
    {{4,5,2},{5,0,1},{5,1,2},{0,0,0}},
    {{2,3,0},{3,4,5},{3,5,0},{0,0,0}},
    {{0,1,5},{1,2,3},{1,3,5},{3,4,5}}};
  u32 c = cat[f];
  int cv[6];
  cv[0] = face[f*3];   cv[2] = face[f*3+1]; cv[4] = face[f*3+2];
  cv[1] = VN + (int)selr[feid[f*3]];
  cv[3] = VN + (int)selr[feid[f*3+1]];
  cv[5] = VN + (int)selr[feid[f*3+2]];
  u32 g  = cr[f] - scal[S_GP + c];
  u32 o1 = scal[S_O1];
  for (int j = 0; j < nfc[c]; ++j) {
    u32 row = scal[S_RS + c] + (u32)j*scal[S_GS + c] + g;
    for (int m = 0; m < 3; ++m) {
      int v = cv[tri[c][j][m]];
      nfi[row*3 + m] = v;
      dout[o1 + row*3 + m] = (float)v;
    }
  }
}

__global__ void k_wne(const int* __restrict__ nfi, const u32* __restrict__ scal,
                      float* __restrict__ dout) {
  int i = blockIdx.x*256 + threadIdx.x;
  u32 NEn = scal[S_NEN];
  if (i >= (int)NEn) return;
  u32 NF = scal[S_NF];
  u32 Vp = (u32)VN + scal[S_NUM];
  u32 o2 = scal[S_O2];
  int a, b;
  if ((u32)i < Vp) { a = i; b = i; }
  else {
    u32 j = (u32)i - Vp;
    u32 blk = j / NF, r = j - blk*NF;
    int i0 = (blk == 0) ? 0 : (blk == 1) ? 1 : 2;
    int i1 = (blk == 0) ? 1 : (blk == 1) ? 2 : 0;
    a = nfi[r*3 + i0]; b = nfi[r*3 + i1];
  }
  dout[o2 + i] = (float)a;
  dout[o2 + NEn + i] = (float)b;
}

__global__ void k_wmask(const u32* __restrict__ sel, const float* __restrict__ Y,
                        const u32* __restrict__ scal, float* __restrict__ dout) {
  int e = blockIdx.x*256 + threadIdx.x;
  if (e >= (int)scal[S_E]) return;
  float y = Y[e];
  float yh = sel[e] ? 1.0f : 0.0f;
  dout[scal[S_O3] + e] = (yh - y) + y;   // straight-through value
}

// ---------------- host-side drivers ----------------
static void run_scan(u32* in, u32* out, u32* sums, int n, hipStream_t st) {
  int nb = (n + 1023) / 1024;
  scan_blocks<<<nb, 256, 0, st>>>(in, out, sums, n);
  scan_sums<<<1, 256, 0, st>>>(sums, nb);
  scan_add<<<nb, 256, 0, st>>>(out, sums, n);
}

static void radix_pass(u32* kin, u32* pin, u32* kout, u32* pout, u32* hist, u32* sums,
                       int n, int nb, int shift, bool haspay, hipStream_t st) {
  k_rhist<<<nb, 256, 0, st>>>(kin, hist, n, shift, nb);
  run_scan(hist, hist, sums, nb*256, st);
  k_rscat<<<nb, 256, 0, st>>>(kin, pin, kout, pout, hist, n, shift, nb, haspay ? 1 : 0);
}

extern "C" void kernel_launch(void* const* d_in, const int* in_sizes, int n_in,
                              void* d_out, int out_size, void* d_ws, size_t ws_size,
                              hipStream_t stream) {
  const float* x    = (const float*)d_in[0];
  const int*   face = (const int*)d_in[1];
  const int*   divp = (const int*)d_in[4];
  const float* W1s  = (const float*)d_in[5];
  const float* W1n  = (const float*)d_in[6];
  const float* b1   = (const float*)d_in[7];
  const float* W2s  = (const float*)d_in[8];
  const float* W2n  = (const float*)d_in[9];
  const float* b2   = (const float*)d_in[10];
  float* out = (float*)d_out;
  u32* W = (u32*)d_ws;

  u32 *A = W+W_A, *B = W+W_B, *FL = W+W_FLAGS, *RK = W+W_RANKU, *UK = W+W_UKEYS;
  u32 *HIST = W+W_HIST, *SUMS = W+W_SUMS, *SCAL = W+W_SCAL;

  // 1) keys + sort + unique
  k_keys<<<NB1, 256, 0, stream>>>(face, A);
  radix_pass(A, nullptr, B, nullptr, HIST, SUMS, K3F, NB1,  0, false, stream);
  radix_pass(B, nullptr, A, nullptr, HIST, SUMS, K3F, NB1,  8, false, stream);
  radix_pass(A, nullptr, B, nullptr, HIST, SUMS, K3F, NB1, 16, false, stream);
  radix_pass(B, nullptr, A, nullptr, HIST, SUMS, K3F, NB1, 24, false, stream);
  k_uflag<<<NB1, 256, 0, stream>>>(A, FL);
  run_scan(FL, RK, SUMS, K3F, stream);
  k_uwrite<<<NB1, 256, 0, stream>>>(A, FL, RK, UK, SCAL, divp);

  // 2) edge nodes, feid, xe
  k_ennode<<<NB1, 256, 0, stream>>>(UK, SCAL, W+W_ENIDX, out);
  k_feid<<<NB1, 256, 0, stream>>>(face, UK, SCAL, W+W_FEID);
  k_xe<<<NB1, 256, 0, stream>>>(x, W+W_ENIDX, SCAL, (float*)(W+W_XE));

  // 3) directed edge list, stable sort by dst -> CSR
  k_elist<<<NB2, 256, 0, stream>>>(W+W_FEID, SCAL, W+W_DSTA, W+W_SRCA);
  radix_pass(W+W_DSTA, W+W_SRCA, W+W_DSTB, W+W_SRCB, HIST, SUMS, NEDG, NB2,  0, true, stream);
  radix_pass(W+W_DSTB, W+W_SRCB, W+W_DSTA, W+W_SRCA, HIST, SUMS, NEDG, NB2,  8, true, stream);
  radix_pass(W+W_DSTA, W+W_SRCA, W+W_DSTB, W+W_SRCB, HIST, SUMS, NEDG, NB2, 16, true, stream);
  k_off<<<1173, 256, 0, stream>>>(W+W_DSTB, SCAL, W+W_OFF);

  // 4) GSN conv layers (deterministic CSR aggregation, fused matmuls)
  k_aggxe<<<NB1, 256, 0, stream>>>(W+W_OFF, W+W_SRCB, (float*)(W+W_XE), SCAL, (float*)(W+W_AGGXE));
  k_l12<<<75000, 256, 0, stream>>>((float*)(W+W_XE), (float*)(W+W_AGGXE), W+W_OFF, SCAL,
                                   W1s, W1n, b1, W2s, W2n,
                                   (float*)(W+W_P), (float*)(W+W_Q));
  k_scores<<<NB1, 256, 0, stream>>>((float*)(W+W_P), (float*)(W+W_Q), W+W_OFF, W+W_SRCB,
                                    b2, SCAL, (float*)(W+W_Y), W+W_YMAP);

  // 5) exact top-k (byte descent) + tie-stable selection
  k_tkinit<<<1, 256, 0, stream>>>(SCAL, HIST);
  for (int byte = 3; byte >= 0; --byte) {
    k_tkhist<<<NB1, 256, 0, stream>>>(W+W_YMAP, SCAL, HIST, byte);
    k_tksel<<<1, 1, 0, stream>>>(SCAL, HIST, byte);
  }
  k_tflag<<<NB1, 256, 0, stream>>>(W+W_YMAP, SCAL, W+W_TFLAG);
  run_scan(W+W_TFLAG, W+W_TIER, SUMS, EMAX, stream);
  k_sel<<<NB1, 256, 0, stream>>>(W+W_YMAP, W+W_TIER, SCAL, W+W_SEL);
  run_scan(W+W_SEL, W+W_SELR, SUMS, EMAX, stream);

  // 6) mesh collapse
  k_cat<<<391, 256, 0, stream>>>(W+W_FEID, W+W_SEL, W+W_CAT);
  k_cathist<<<NBC, 256, 0, stream>>>(W+W_CAT, W+W_CATH);
  k_catoff<<<1, 1, 0, stream>>>(W+W_CATH, SCAL);
  k_catrank<<<NBC, 256, 0, stream>>>(W+W_CAT, W+W_CATH, W+W_CATR);
  k_wfaces<<<391, 256, 0, stream>>>(face, W+W_CAT, W+W_CATR, W+W_FEID, W+W_SELR, SCAL,
                                    (int*)(W+W_NFI), out);
  k_wne<<<5118, 256, 0, stream>>>((int*)(W+W_NFI), SCAL, out);
  k_wmask<<<NB1, 256, 0, stream>>>(W+W_SEL, (float*)(W+W_Y), SCAL, out);
}

// Round 2
// 629.986 us; speedup vs baseline: 5.3080x; 5.3080x over previous
//
#include <hip/hip_runtime.h>
#include <stdint.h>

typedef uint32_t u32;
typedef uint64_t u64;

#define VN 50000
#define FN 100000
#define K3F 300000
#define EMAX 300000
#define NEDG 900000
#define NB1 1172          // ceil(300000/256)
#define NB2 3516          // ceil(900000/256)
#define NBC 98            // ceil(100000/1024)
#define NBH 293           // ceil(300000/1024) — tkhist blocks
#define PADKEY 0x00FFFFFFu

// ---------------- workspace layout (u32 units) ----------------
#define W_A      0u        // 300000  (biased keys / sorted keys)   [overlaid by DSTA later]
#define W_B      300000u   // 300000  ping buffer
#define W_FLAGS  600000u
#define W_RANKU  900000u
#define W_UKEYS  1200000u
#define W_DSTA   0u        // 900000  edge-list dst (overlays A/B/FLAGS)
#define W_SRCA   900000u   // 900000  (overlays RANKU/UKEYS/pad)
#define W_DSTB   1800000u
#define W_SRCB   2700000u
#define W_FEID   3600000u  // 300000
#define W_ENIDX  3900000u  // 600000
#define W_XE     4500000u  // 900000 f32
#define W_OFF    5400000u  // 300001
#define W_AGGXE  5700004u  // 900000 f32
#define W_P      6600004u  // 600000 f32
#define W_Q      7200004u  // 600000 f32
#define W_Y      7800004u  // 300000 f32
#define W_YMAP   8100004u
#define W_TFLAG  8400004u
#define W_TIER   8700004u
#define W_SEL    9000004u
#define W_SELR   9300004u
#define W_CAT    9600004u  // 100000
#define W_CATR   9700004u  // 100000
#define W_NFI    9800004u  // 1200000 int (new faces)
#define W_HIST   11000004u // 900096
#define W_SUMS   11900100u // 4096
#define W_CATH   11904196u // 1024
#define W_SCAL   11905220u // 64

#define S_E 0
#define S_NUM 1
#define S_PFX 2
#define S_KREM 3
#define S_TU 4
#define S_R 5
#define S_NF 6
#define S_NEN 7
#define S_O1 8
#define S_O2 9
#define S_O3 10
#define S_RS 16
#define S_GS 24
#define S_GP 32

// ---------------- threefry2x32, key = (0, 42) ----------------
__device__ __forceinline__ void tf2x32(u32 x0, u32 x1, u32& o0, u32& o1) {
  const u32 ks0 = 0u, ks1 = 42u, ks2 = 0x1BD11BDAu ^ 0u ^ 42u;
  x0 += ks0; x1 += ks1;
#define TFR(r) { x0 += x1; x1 = (x1<<(r))|(x1>>(32-(r))); x1 ^= x0; }
  TFR(13) TFR(15) TFR(26) TFR(6)   x0 += ks1; x1 += ks2 + 1u;
  TFR(17) TFR(29) TFR(16) TFR(24)  x0 += ks2; x1 += ks0 + 2u;
  TFR(13) TFR(15) TFR(26) TFR(6)   x0 += ks0; x1 += ks1 + 3u;
  TFR(17) TFR(29) TFR(16) TFR(24)  x0 += ks1; x1 += ks2 + 4u;
  TFR(13) TFR(15) TFR(26) TFR(6)   x0 += ks2; x1 += ks0 + 5u;
#undef TFR
  o0 = x0; o1 = x1;
}

// ---------------- generic exclusive scan (u32) ----------------
__global__ void scan_blocks(const u32* __restrict__ in, u32* __restrict__ out,
                            u32* __restrict__ sums, int n) {
  __shared__ u32 lds[256];
  int t = threadIdx.x;
  int base = blockIdx.x*1024 + t*4;
  u32 v[4]; u32 tot = 0;
  for (int k = 0; k < 4; ++k) { v[k] = (base+k < n) ? in[base+k] : 0u; tot += v[k]; }
  lds[t] = tot; __syncthreads();
  for (int o = 1; o < 256; o <<= 1) {
    u32 x = (t >= o) ? lds[t-o] : 0u; __syncthreads();
    lds[t] += x; __syncthreads();
  }
  u32 excl = lds[t] - tot;
  if (t == 255) sums[blockIdx.x] = lds[255];
  u32 run = excl;
  for (int k = 0; k < 4; ++k) { if (base+k < n) out[base+k] = run; run += v[k]; }
}

__global__ void scan_sums(u32* __restrict__ s, int nb) {
  __shared__ u32 lds[256];
  __shared__ u32 carry;
  int t = threadIdx.x;
  if (t == 0) carry = 0;
  __syncthreads();
  for (int base = 0; base < nb; base += 1024) {
    int idx = base + t*4;
    u32 v[4]; u32 tot = 0;
    for (int k = 0; k < 4; ++k) { v[k] = (idx+k < nb) ? s[idx+k] : 0u; tot += v[k]; }
    lds[t] = tot; __syncthreads();
    for (int o = 1; o < 256; o <<= 1) {
      u32 x = (t >= o) ? lds[t-o] : 0u; __syncthreads();
      lds[t] += x; __syncthreads();
    }
    u32 excl = lds[t] - tot;
    u32 ctot = lds[255];
    u32 c = carry;
    __syncthreads();
    u32 run = c + excl;
    for (int k = 0; k < 4; ++k) { if (idx+k < nb) s[idx+k] = run; run += v[k]; }
    if (t == 0) carry = c + ctot;
    __syncthreads();
  }
}

__global__ void scan_add(u32* __restrict__ out, const u32* __restrict__ sums, int n) {
  int base = blockIdx.x*1024 + threadIdx.x*4;
  u32 a = sums[blockIdx.x];
  for (int k = 0; k < 4; ++k) if (base+k < n) out[base+k] += a;
}

// ---------------- radix sort (8-bit LSD, stable) ----------------
__global__ void k_rhist(const u32* __restrict__ keys, u32* __restrict__ hist,
                        int n, int shift, int nb) {
  __shared__ u32 h[256];
  int t = threadIdx.x;
  h[t] = 0; __syncthreads();
  int i = blockIdx.x*256 + t;
  if (i < n) atomicAdd(&h[(keys[i]>>shift)&255u], 1u);
  __syncthreads();
  hist[(u32)t*nb + blockIdx.x] = h[t];
}

__global__ void k_rscat(const u32* __restrict__ keys, const u32* __restrict__ pay,
                        u32* __restrict__ okeys, u32* __restrict__ opay,
                        const u32* __restrict__ hist, int n, int shift, int nb, int haspay) {
  __shared__ u64 ball[4][8];
  __shared__ u64 vmask[4];
  int t = threadIdx.x, w = t>>6, lane = t&63;
  int i = blockIdx.x*256 + t;
  bool valid = i < n;
  u32 k = valid ? keys[i] : 0u;
  u32 d = (k>>shift)&255u;
  for (int bit = 0; bit < 8; ++bit) {
    u64 bm = __ballot(valid && ((d>>bit)&1u));
    if (lane == 0) ball[w][bit] = bm;
  }
  u64 vb = __ballot(valid ? 1 : 0);
  if (lane == 0) vmask[w] = vb;
  __syncthreads();
  if (valid) {
    u32 rank = 0;
    for (int ww = 0; ww < w; ++ww) {
      u64 m = vmask[ww];
      for (int bit = 0; bit < 8; ++bit) { u64 bb = ball[ww][bit]; m &= ((d>>bit)&1u) ? bb : ~bb; }
      rank += (u32)__popcll(m);
    }
    u64 m = vmask[w];
    for (int bit = 0; bit < 8; ++bit) { u64 bb = ball[w][bit]; m &= ((d>>bit)&1u) ? bb : ~bb; }
    rank += (u32)__popcll(m & ((1ull<<lane)-1ull));
    u32 pos = hist[d*(u32)nb + blockIdx.x] + rank;
    okeys[pos] = k;
    if (haspay) opay[pos] = pay[i];
  }
}

// ---------------- pipeline kernels ----------------
__global__ void k_keys(const int* __restrict__ face, u32* __restrict__ keys) {
  int i = blockIdx.x*256 + threadIdx.x;
  if (i >= K3F) return;
  int s = i / FN, f = i - s*FN;
  int v0 = face[f*3 + s];
  int v1 = face[f*3 + (s == 2 ? 0 : s+1)];
  int a = min(v0, v1), b = max(v0, v1);
  u32 key = (u32)a * (u32)VN + (u32)b;   // int32 wraparound, matches jnp
  keys[i] = key ^ 0x80000000u;           // biased: unsigned order == signed order
}

__global__ void k_uflag(const u32* __restrict__ sk, u32* __restrict__ flags) {
  int i = blockIdx.x*256 + threadIdx.x;
  if (i >= K3F) return;
  flags[i] = (i == 0 || sk[i] != sk[i-1]) ? 1u : 0u;
}

__global__ void k_uwrite(const u32* __restrict__ sk, const u32* __restrict__ flags,
                         const u32* __restrict__ rank, u32* __restrict__ ukeys,
                         u32* __restrict__ scal, const int* __restrict__ divp) {
  int i = blockIdx.x*256 + threadIdx.x;
  if (i >= K3F) return;
  if (flags[i]) ukeys[rank[i]] = sk[i];
  if (i == K3F-1) { u32 E = rank[i] + flags[i]; scal[S_E] = E; scal[S_NUM] = E / (u32)divp[0]; }
}

__global__ void k_ennode(const u32* __restrict__ ukeys, const u32* __restrict__ scal,
                         u32* __restrict__ enidx, float* __restrict__ dout) {
  int e = blockIdx.x*256 + threadIdx.x;
  if (e >= (int)scal[S_E]) return;
  int k = (int)(ukeys[e] ^ 0x80000000u);
  long long kk = (long long)k;
  long long qq = (kk - (kk < 0 ? (long long)(VN-1) : 0ll)) / VN; // floor div
  int q = (int)qq;
  int r = (int)(kk - qq * VN);
  dout[2*e]   = (float)q;
  dout[2*e+1] = (float)r;
  enidx[2*e]   = (u32)(q < 0 ? q + VN : q);  // numpy-style negative index wrap
  enidx[2*e+1] = (u32)r;
}

__global__ void k_feid(const int* __restrict__ face, const u32* __restrict__ ukeys,
                       const u32* __restrict__ scal, u32* __restrict__ feid) {
  int i = blockIdx.x*256 + threadIdx.x;
  if (i >= K3F) return;
  int s = i / FN, f = i - s*FN;
  int v0 = face[f*3 + s];
  int v1 = face[f*3 + (s == 2 ? 0 : s+1)];
  int a = min(v0, v1), b = max(v0, v1);
  u32 kb = ((u32)a * (u32)VN + (u32)b) ^ 0x80000000u;
  u32 lo = 0, hi = scal[S_E];
  while (lo < hi) { u32 mid = (lo+hi)>>1; if (ukeys[mid] < kb) lo = mid+1; else hi = mid; }
  feid[f*3 + s] = lo;
}

__global__ void k_xe(const float* __restrict__ x, const u32* __restrict__ enidx,
                     const u32* __restrict__ scal, float* __restrict__ xe) {
  int e = blockIdx.x*256 + threadIdx.x;
  if (e >= (int)scal[S_E]) return;
  u32 i0 = enidx[2*e], i1 = enidx[2*e+1];
  for (int c = 0; c < 3; ++c) xe[e*3+c] = 0.5f*(x[i0*3+c] + x[i1*3+c]);
}

__global__ void k_elist(const u32* __restrict__ feid, const u32* __restrict__ scal,
                        u32* __restrict__ dst, u32* __restrict__ src) {
  int i = blockIdx.x*256 + threadIdx.x;
  if (i >= NEDG) return;
  const int sb[6] = {0,1,1,2,2,0};
  const int db[6] = {1,0,2,1,0,2};
  if (i < 6*FN) {
    int b = i / FN, f = i - b*FN;
    src[i] = feid[f*3 + sb[b]];
    dst[i] = feid[f*3 + db[b]];
  } else {
    int e = i - 6*FN;
    if (e < (int)scal[S_E]) { src[i] = (u32)e; dst[i] = (u32)e; }
    else { src[i] = 0u; dst[i] = PADKEY; }
  }
}

__global__ void k_off(const u32* __restrict__ dsts, const u32* __restrict__ scal,
                      u32* __restrict__ off) {
  int e = blockIdx.x*256 + threadIdx.x;
  if (e > (int)scal[S_E]) return;
  u32 key = (u32)e, lo = 0, hi = NEDG;
  while (lo < hi) { u32 mid = (lo+hi)>>1; if (dsts[mid] < key) lo = mid+1; else hi = mid; }
  off[e] = lo;
}

__global__ void k_aggxe(const u32* __restrict__ off, const u32* __restrict__ srcs,
                        const float* __restrict__ xe, const u32* __restrict__ scal,
                        float* __restrict__ agg) {
  int e = blockIdx.x*256 + threadIdx.x;
  if (e >= (int)scal[S_E]) return;
  u32 s = off[e], t = off[e+1];
  float c0 = 0.f, c1 = 0.f, c2 = 0.f;
  for (u32 j = s; j < t; ++j) {               // sequential in original edge order (stable sort)
    u32 u = srcs[j];
    c0 += xe[u*3]; c1 += xe[u*3+1]; c2 += xe[u*3+2];
  }
  agg[e*3] = c0; agg[e*3+1] = c1; agg[e*3+2] = c2;
}

// fused layer1(relu-gsnconv) + projection to W2s/W2n — one wave per edge-node
__global__ void k_l12(const float* __restrict__ xe, const float* __restrict__ agg,
                      const u32* __restrict__ off, const u32* __restrict__ scal,
                      const float* __restrict__ W1s, const float* __restrict__ W1n,
                      const float* __restrict__ b1,
                      const float* __restrict__ W2s, const float* __restrict__ W2n,
                      float* __restrict__ P, float* __restrict__ Q) {
  int w = threadIdx.x >> 6, lane = threadIdx.x & 63;
  int e = blockIdx.x*4 + w;
  if (e >= (int)scal[S_E]) return;
  float x0 = xe[e*3], x1 = xe[e*3+1], x2 = xe[e*3+2];
  float dg = (float)(off[e+1] - off[e]);
  float m0 = agg[e*3]/dg, m1 = agg[e*3+1]/dg, m2 = agg[e*3+2]/dg;
  float p0 = 0.f, p1 = 0.f, q0 = 0.f, q1 = 0.f;
  for (int kk = 0; kk < 4; ++kk) {
    int hid = lane + 64*kk;
    float s1 = x0*W1s[hid] + x1*W1s[256+hid] + x2*W1s[512+hid];
    float s2 = m0*W1n[hid] + m1*W1n[256+hid] + m2*W1n[512+hid];
    float h = fmaxf(s1 + s2 + b1[hid], 0.0f);
    p0 += h*W2s[hid*2];  p1 += h*W2s[hid*2+1];
    q0 += h*W2n[hid*2];  q1 += h*W2n[hid*2+1];
  }
  for (int o = 32; o; o >>= 1) {
    p0 += __shfl_xor(p0, o); p1 += __shfl_xor(p1, o);
    q0 += __shfl_xor(q0, o); q1 += __shfl_xor(q1, o);
  }
  if (lane == 0) { P[2*e] = p0; P[2*e+1] = p1; Q[2*e] = q0; Q[2*e+1] = q1; }
}

__global__ void k_scores(const float* __restrict__ P, const float* __restrict__ Q,
                         const u32* __restrict__ off, const u32* __restrict__ srcs,
                         const float* __restrict__ b2, const u32* __restrict__ scal,
                         float* __restrict__ Y, u32* __restrict__ ymap) {
  int e = blockIdx.x*256 + threadIdx.x;
  u32 E = scal[S_E];
  if (e >= (int)E) return;
  u32 s = off[e], t = off[e+1];
  float dg = (float)(t - s);
  float a0 = 0.f, a1 = 0.f;
  for (u32 j = s; j < t; ++j) { u32 u = srcs[j]; a0 += Q[2*u]; a1 += Q[2*u+1]; }
  float z0 = P[2*e]   + a0/dg + b2[0];
  float z1 = P[2*e+1] + a1/dg + b2[1];
  float l0 = 1.0f/(1.0f + expf(-z0));
  float l1 = 1.0f/(1.0f + expf(-z1));
  // JAX partitionable threefry: bits(i) = o0^o1 of threefry(key=(0,42), counts=(i>>32, i&...))
  u32 g0b, g1b;
  { u32 o0,o1; tf2x32(0u, 2u*(u32)e,      o0, o1); g0b = o0 ^ o1; }
  { u32 o0,o1; tf2x32(0u, 2u*(u32)e + 1u, o0, o1); g1b = o0 ^ o1; }
  float U0 = __uint_as_float((g0b>>9) | 0x3f800000u) - 1.0f;
  float U1 = __uint_as_float((g1b>>9) | 0x3f800000u) - 1.0f;
  float g0 = -logf(-logf(U0 + 1e-20f) + 1e-20f);
  float g1 = -logf(-logf(U1 + 1e-20f) + 1e-20f);
  float A0 = (l0 + g0)/0.1f;
  float A1 = (l1 + g1)/0.1f;
  float mx = fmaxf(A0, A1);
  float e0 = expf(A0-mx), e1 = expf(A1-mx);
  float y = e0/(e0+e1);
  Y[e] = y;
  ymap[e] = __float_as_uint(y) | 0x80000000u;   // monotone map (y >= 0)
}

// ---------------- exact top-k threshold (byte-wise descent) ----------------
__global__ void k_tkinit(u32* __restrict__ scal, u32* __restrict__ hist) {
  int t = threadIdx.x;
  if (t < 256) hist[t] = 0u;
  if (t == 0) { scal[S_PFX] = 0u; scal[S_KREM] = scal[S_NUM]; }
}

// two-level histogram: LDS per block, then one global atomic per non-zero bucket.
// (v1 did 300k same-line global atomics at byte=3 -> 1.59 ms of serialized L2 RMW)
__global__ void k_tkhist(const u32* __restrict__ ymap, const u32* __restrict__ scal,
                         u32* __restrict__ hist, int byte) {
  __shared__ u32 h[256];
  int t = threadIdx.x;
  h[t] = 0u; __syncthreads();
  int E = (int)scal[S_E];
  u32 pfx = scal[S_PFX];
  int base = blockIdx.x*1024;
  for (int k = 0; k < 4; ++k) {
    int e = base + k*256 + t;
    if (e < E) {
      u32 u = ymap[e];
      bool match = (byte == 3) || ((u >> ((byte+1)*8)) == pfx);
      if (match) atomicAdd(&h[(u >> (byte*8)) & 255u], 1u);
    }
  }
  __syncthreads();
  u32 c = h[t];
  if (c) atomicAdd(&hist[t], c);
}

__global__ void k_tksel(u32* __restrict__ scal, u32* __restrict__ hist, int byte) {
  if (threadIdx.x != 0 || blockIdx.x != 0) return;
  u32 krem = scal[S_KREM], pfx = scal[S_PFX];
  u32 chosen = 0;
  for (int b = 255; b >= 0; --b) {
    u32 c = hist[b];
    if (krem <= c) { chosen = (u32)b; break; }
    krem -= c;
  }
  pfx = (pfx << 8) | chosen;
  scal[S_PFX] = pfx; scal[S_KREM] = krem;
  if (byte == 0) { scal[S_TU] = pfx; scal[S_R] = krem; }
  for (int i = 0; i < 256; ++i) hist[i] = 0u;
}

__global__ void k_tflag(const u32* __restrict__ ymap, const u32* __restrict__ scal,
                        u32* __restrict__ tf) {
  int e = blockIdx.x*256 + threadIdx.x;
  if (e >= EMAX) return;
  tf[e] = (e < (int)scal[S_E] && ymap[e] == scal[S_TU]) ? 1u : 0u;
}

__global__ void k_sel(const u32* __restrict__ ymap, const u32* __restrict__ tier,
                      const u32* __restrict__ scal, u32* __restrict__ sel) {
  int e = blockIdx.x*256 + threadIdx.x;
  if (e >= EMAX) return;
  u32 v = 0;
  if (e < (int)scal[S_E]) {
    u32 u = ymap[e];
    v = (u > scal[S_TU]) || (u == scal[S_TU] && tier[e] < scal[S_R]);
  }
  sel[e] = v ? 1u : 0u;
}

// ---------------- mesh collapse ----------------
__global__ void k_cat(const u32* __restrict__ feid, const u32* __restrict__ sel,
                      u32* __restrict__ cat) {
  int f = blockIdx.x*256 + threadIdx.x;
  if (f >= FN) return;
  u32 m0 = sel[feid[f*3]], m1 = sel[feid[f*3+1]], m2 = sel[feid[f*3+2]];
  u32 pen = m0 + m1 + m2;
  u32 psi = m1 + 2u*m2;
  u32 c = (pen == 0) ? 0u : (pen == 1) ? (1u+psi) : (pen == 2) ? (3u+psi) : 7u;
  cat[f] = c;
}

__global__ void k_cathist(const u32* __restrict__ cat, u32* __restrict__ ch) {
  __shared__ u32 h[8];
  int t = threadIdx.x;
  if (t < 8) h[t] = 0u;
  __syncthreads();
  int base = blockIdx.x*1024 + t*4;
  for (int k = 0; k < 4; ++k) if (base+k < FN) atomicAdd(&h[cat[base+k]], 1u);
  __syncthreads();
  if (t < 8) ch[(u32)t*NBC + blockIdx.x] = h[t];
}

__global__ void k_catoff(u32* __restrict__ ch, u32* __restrict__ scal) {
  if (threadIdx.x || blockIdx.x) return;
  u32 tot[8];
  for (int c = 0; c < 8; ++c) { u32 s = 0; for (int b = 0; b < NBC; ++b) s += ch[c*NBC+b]; tot[c] = s; }
  u32 run = 0;
  for (int i = 0; i < 8*NBC; ++i) { u32 v = ch[i]; ch[i] = run; run += v; }
  u32 n0 = tot[0], n1 = tot[1]+tot[2]+tot[3], n2 = tot[4]+tot[5]+tot[6], n3 = tot[7];
  u32 NF = n0 + 2u*n1 + 3u*n2 + 4u*n3;
  u32 E = scal[S_E], num = scal[S_NUM];
  u32 NEn = (u32)VN + num + 3u*NF;
  scal[S_NF] = NF; scal[S_NEN] = NEn;
  scal[S_O1] = 2u*E;
  scal[S_O2] = 2u*E + 3u*NF;
  scal[S_O3] = 2u*E + 3u*NF + 2u*NEn;
  u32 RS[8] = {0u, n0,n0,n0, n0+2u*n1, n0+2u*n1, n0+2u*n1, n0+2u*n1+3u*n2};
  u32 GS[8] = {0u, n1,n1,n1, n2,n2,n2, n3};
  u32 GP[8] = {0u, n0,n0,n0, n0+n1, n0+n1, n0+n1, n0+n1+n2};
  for (int i = 0; i < 8; ++i) { scal[S_RS+i] = RS[i]; scal[S_GS+i] = GS[i]; scal[S_GP+i] = GP[i]; }
}

__global__ void k_catrank(const u32* __restrict__ cat, const u32* __restrict__ ch,
                          u32* __restrict__ cr) {
  __shared__ u32 lds[256];
  int t = threadIdx.x;
  int base = blockIdx.x*1024 + t*4;
  u32 cc[4], loc[4];
  u32 cnt[8] = {0,0,0,0,0,0,0,0};
  for (int k = 0; k < 4; ++k) {
    int i = base + k;
    if (i < FN) { u32 c = cat[i]; cc[k] = c; loc[k] = cnt[c]++; }
    else cc[k] = 8u;
  }
  u32 tb[8];
  for (int c = 0; c < 8; ++c) {
    lds[t] = cnt[c]; __syncthreads();
    for (int o = 1; o < 256; o <<= 1) {
      u32 x = (t >= o) ? lds[t-o] : 0u; __syncthreads();
      lds[t] += x; __syncthreads();
    }
    tb[c] = lds[t] - cnt[c];
    __syncthreads();
  }
  for (int k = 0; k < 4; ++k) {
    int i = base + k;
    if (i < FN) { u32 c = cc[k]; cr[i] = ch[c*NBC + blockIdx.x] + tb[c] + loc[k]; }
  }
}

__global__ void k_wfaces(const int* __restrict__ face, const u32* __restrict__ cat,
                         const u32* __restrict__ cr, const u32* __restrict__ feid,
                         const u32* __restrict__ selr, const u32* __restrict__ scal,
                         int* __restrict__ nfi, float* __restrict__ dout) {
  int f = blockIdx.x*256 + threadIdx.x;
  if (f >= FN) return;
  const int nfc[8] = {1,2,2,2,3,3,3,4};
  const int tri[8][4][3] = {
    {{0,2,4},{0,0,0},{0,0,0},{0,0,0}},
    {{0,1,4},{1,2,4},{0,0,0},{0,0,0}},
    {{2,3,0},{3,4,0},{0,0,0},{0,0,0}},
    {{4,5,2},{5,0,2},{0,0,0},{0,0,0}},
    {{0,1,4},{1,2,3},{1,3,4},{0,0,0}},
    {{4,5,2},{5,0,1},{5,1,2},{0,0,0}},
    {{2,3,0},{3,4,5},{3,5,0},{0,0,0}},
    {{0,1,5},{1,2,3},{1,3,5},{3,4,5}}};
  u32 c = cat[f];
  int cv[6];
  cv[0] = face[f*3];   cv[2] = face[f*3+1]; cv[4] = face[f*3+2];
  cv[1] = VN + (int)selr[feid[f*3]];
  cv[3] = VN + (int)selr[feid[f*3+1]];
  cv[5] = VN + (int)selr[feid[f*3+2]];
  u32 g  = cr[f] - scal[S_GP + c];
  u32 o1 = scal[S_O1];
  for (int j = 0; j < nfc[c]; ++j) {
    u32 row = scal[S_RS + c] + (u32)j*scal[S_GS + c] + g;
    for (int m = 0; m < 3; ++m) {
      int v = cv[tri[c][j][m]];
      nfi[row*3 + m] = v;
      dout[o1 + row*3 + m] = (float)v;
    }
  }
}

__global__ void k_wne(const int* __restrict__ nfi, const u32* __restrict__ scal,
                      float* __restrict__ dout) {
  int i = blockIdx.x*256 + threadIdx.x;
  u32 NEn = scal[S_NEN];
  if (i >= (int)NEn) return;
  u32 NF = scal[S_NF];
  u32 Vp = (u32)VN + scal[S_NUM];
  u32 o2 = scal[S_O2];
  int a, b;
  if ((u32)i < Vp) { a = i; b = i; }
  else {
    u32 j = (u32)i - Vp;
    u32 blk = j / NF, r = j - blk*NF;
    int i0 = (blk == 0) ? 0 : (blk == 1) ? 1 : 2;
    int i1 = (blk == 0) ? 1 : (blk == 1) ? 2 : 0;
    a = nfi[r*3 + i0]; b = nfi[r*3 + i1];
  }
  dout[o2 + i] = (float)a;
  dout[o2 + NEn + i] = (float)b;
}

__global__ void k_wmask(const u32* __restrict__ sel, const float* __restrict__ Y,
                        const u32* __restrict__ scal, float* __restrict__ dout) {
  int e = blockIdx.x*256 + threadIdx.x;
  if (e >= (int)scal[S_E]) return;
  float y = Y[e];
  float yh = sel[e] ? 1.0f : 0.0f;
  dout[scal[S_O3] + e] = (yh - y) + y;   // straight-through value
}

// ---------------- host-side drivers ----------------
static void run_scan(u32* in, u32* out, u32* sums, int n, hipStream_t st) {
  int nb = (n + 1023) / 1024;
  scan_blocks<<<nb, 256, 0, st>>>(in, out, sums, n);
  scan_sums<<<1, 256, 0, st>>>(sums, nb);
  scan_add<<<nb, 256, 0, st>>>(out, sums, n);
}

static void radix_pass(u32* kin, u32* pin, u32* kout, u32* pout, u32* hist, u32* sums,
                       int n, int nb, int shift, bool haspay, hipStream_t st) {
  k_rhist<<<nb, 256, 0, st>>>(kin, hist, n, shift, nb);
  run_scan(hist, hist, sums, nb*256, st);
  k_rscat<<<nb, 256, 0, st>>>(kin, pin, kout, pout, hist, n, shift, nb, haspay ? 1 : 0);
}

extern "C" void kernel_launch(void* const* d_in, const int* in_sizes, int n_in,
                              void* d_out, int out_size, void* d_ws, size_t ws_size,
                              hipStream_t stream) {
  const float* x    = (const float*)d_in[0];
  const int*   face = (const int*)d_in[1];
  const int*   divp = (const int*)d_in[4];
  const float* W1s  = (const float*)d_in[5];
  const float* W1n  = (const float*)d_in[6];
  const float* b1   = (const float*)d_in[7];
  const float* W2s  = (const float*)d_in[8];
  const float* W2n  = (const float*)d_in[9];
  const float* b2   = (const float*)d_in[10];
  float* out = (float*)d_out;
  u32* W = (u32*)d_ws;

  u32 *A = W+W_A, *B = W+W_B, *FL = W+W_FLAGS, *RK = W+W_RANKU, *UK = W+W_UKEYS;
  u32 *HIST = W+W_HIST, *SUMS = W+W_SUMS, *SCAL = W+W_SCAL;

  // 1) keys + sort + unique
  k_keys<<<NB1, 256, 0, stream>>>(face, A);
  radix_pass(A, nullptr, B, nullptr, HIST, SUMS, K3F, NB1,  0, false, stream);
  radix_pass(B, nullptr, A, nullptr, HIST, SUMS, K3F, NB1,  8, false, stream);
  radix_pass(A, nullptr, B, nullptr, HIST, SUMS, K3F, NB1, 16, false, stream);
  radix_pass(B, nullptr, A, nullptr, HIST, SUMS, K3F, NB1, 24, false, stream);
  k_uflag<<<NB1, 256, 0, stream>>>(A, FL);
  run_scan(FL, RK, SUMS, K3F, stream);
  k_uwrite<<<NB1, 256, 0, stream>>>(A, FL, RK, UK, SCAL, divp);

  // 2) edge nodes, feid, xe
  k_ennode<<<NB1, 256, 0, stream>>>(UK, SCAL, W+W_ENIDX, out);
  k_feid<<<NB1, 256, 0, stream>>>(face, UK, SCAL, W+W_FEID);
  k_xe<<<NB1, 256, 0, stream>>>(x, W+W_ENIDX, SCAL, (float*)(W+W_XE));

  // 3) directed edge list, stable sort by dst -> CSR
  k_elist<<<NB2, 256, 0, stream>>>(W+W_FEID, SCAL, W+W_DSTA, W+W_SRCA);
  radix_pass(W+W_DSTA, W+W_SRCA, W+W_DSTB, W+W_SRCB, HIST, SUMS, NEDG, NB2,  0, true, stream);
  radix_pass(W+W_DSTB, W+W_SRCB, W+W_DSTA, W+W_SRCA, HIST, SUMS, NEDG, NB2,  8, true, stream);
  radix_pass(W+W_DSTA, W+W_SRCA, W+W_DSTB, W+W_SRCB, HIST, SUMS, NEDG, NB2, 16, true, stream);
  k_off<<<1173, 256, 0, stream>>>(W+W_DSTB, SCAL, W+W_OFF);

  // 4) GSN conv layers (deterministic CSR aggregation, fused matmuls)
  k_aggxe<<<NB1, 256, 0, stream>>>(W+W_OFF, W+W_SRCB, (float*)(W+W_XE), SCAL, (float*)(W+W_AGGXE));
  k_l12<<<75000, 256, 0, stream>>>((float*)(W+W_XE), (float*)(W+W_AGGXE), W+W_OFF, SCAL,
                                   W1s, W1n, b1, W2s, W2n,
                                   (float*)(W+W_P), (float*)(W+W_Q));
  k_scores<<<NB1, 256, 0, stream>>>((float*)(W+W_P), (float*)(W+W_Q), W+W_OFF, W+W_SRCB,
                                    b2, SCAL, (float*)(W+W_Y), W+W_YMAP);

  // 5) exact top-k (byte descent) + tie-stable selection
  k_tkinit<<<1, 256, 0, stream>>>(SCAL, HIST);
  for (int byte = 3; byte >= 0; --byte) {
    k_tkhist<<<NBH, 256, 0, stream>>>(W+W_YMAP, SCAL, HIST, byte);
    k_tksel<<<1, 1, 0, stream>>>(SCAL, HIST, byte);
  }
  k_tflag<<<NB1, 256, 0, stream>>>(W+W_YMAP, SCAL, W+W_TFLAG);
  run_scan(W+W_TFLAG, W+W_TIER, SUMS, EMAX, stream);
  k_sel<<<NB1, 256, 0, stream>>>(W+W_YMAP, W+W_TIER, SCAL, W+W_SEL);
  run_scan(W+W_SEL, W+W_SELR, SUMS, EMAX, stream);

  // 6) mesh collapse
  k_cat<<<391, 256, 0, stream>>>(W+W_FEID, W+W_SEL, W+W_CAT);
  k_cathist<<<NBC, 256, 0, stream>>>(W+W_CAT, W+W_CATH);
  k_catoff<<<1, 1, 0, stream>>>(W+W_CATH, SCAL);
  k_catrank<<<NBC, 256, 0, stream>>>(W+W_CAT, W+W_CATH, W+W_CATR);
  k_wfaces<<<391, 256, 0, stream>>>(face, W+W_CAT, W+W_CATR, W+W_FEID, W+W_SELR, SCAL,
                                    (int*)(W+W_NFI), out);
  k_wne<<<5118, 256, 0, stream>>>((int*)(W+W_NFI), SCAL, out);
  k_wmask<<<NB1, 256, 0, stream>>>(W+W_SEL, (float*)(W+W_Y), SCAL, out);
}

// Round 3
// 502.774 us; speedup vs baseline: 6.6510x; 1.2530x over previous
//
#include <hip/hip_runtime.h>
#include <stdint.h>

typedef uint32_t u32;
typedef uint64_t u64;

#define VN 50000
#define FN 100000
#define K3F 300000
#define EMAX 300000
#define NEDG 900000
#define NB1 1172          // ceil(300000/256)
#define NB2 3516          // ceil(900000/256)
#define NBC 98            // ceil(100000/1024)
#define NBH 293           // ceil(300000/1024) — tkhist blocks
#define PADKEY 0x00FFFFFFu

// ---------------- workspace layout (u32 units) ----------------
#define W_A      0u        // 300000  (biased keys / sorted keys)   [overlaid by DSTA later]
#define W_B      300000u   // 300000  ping buffer
#define W_FLAGS  600000u
#define W_RANKU  900000u
#define W_UKEYS  1200000u
#define W_DSTA   0u        // 900000  edge-list dst (overlays A/B/FLAGS)
#define W_SRCA   900000u   // 900000  (overlays RANKU/UKEYS/pad)
#define W_DSTB   1800000u
#define W_SRCB   2700000u
#define W_FEID   3600000u  // 300000
#define W_ENIDX  3900000u  // 600000
#define W_XE     4500000u  // 900000 f32
#define W_OFF    5400000u  // 300001
#define W_PK     5700004u  // 3072 f32 packed weights (reuses old AGGXE slot)
#define W_P      6600004u  // 600000 f32
#define W_Q      7200004u  // 600000 f32
#define W_Y      7800004u  // 300000 f32
#define W_YMAP   8100004u
#define W_TFLAG  8400004u
#define W_TIER   8700004u
#define W_SEL    9000004u
#define W_SELR   9300004u
#define W_CAT    9600004u  // 100000
#define W_CATR   9700004u  // 100000
#define W_NFI    9800004u  // 1200000 int (new faces)
#define W_HIST   11000004u // 900096
#define W_SUMS   11900100u // 4096
#define W_CATH   11904196u // 1024
#define W_SCAL   11905220u // 64

#define S_E 0
#define S_NUM 1
#define S_PFX 2
#define S_KREM 3
#define S_TU 4
#define S_R 5
#define S_NF 6
#define S_NEN 7
#define S_O1 8
#define S_O2 9
#define S_O3 10
#define S_RS 16
#define S_GS 24
#define S_GP 32

// ---------------- threefry2x32, key = (0, 42) ----------------
__device__ __forceinline__ void tf2x32(u32 x0, u32 x1, u32& o0, u32& o1) {
  const u32 ks0 = 0u, ks1 = 42u, ks2 = 0x1BD11BDAu ^ 0u ^ 42u;
  x0 += ks0; x1 += ks1;
#define TFR(r) { x0 += x1; x1 = (x1<<(r))|(x1>>(32-(r))); x1 ^= x0; }
  TFR(13) TFR(15) TFR(26) TFR(6)   x0 += ks1; x1 += ks2 + 1u;
  TFR(17) TFR(29) TFR(16) TFR(24)  x0 += ks2; x1 += ks0 + 2u;
  TFR(13) TFR(15) TFR(26) TFR(6)   x0 += ks0; x1 += ks1 + 3u;
  TFR(17) TFR(29) TFR(16) TFR(24)  x0 += ks1; x1 += ks2 + 4u;
  TFR(13) TFR(15) TFR(26) TFR(6)   x0 += ks2; x1 += ks0 + 5u;
#undef TFR
  o0 = x0; o1 = x1;
}

// ---------------- generic exclusive scan (u32) ----------------
__global__ void scan_blocks(const u32* __restrict__ in, u32* __restrict__ out,
                            u32* __restrict__ sums, int n) {
  __shared__ u32 lds[256];
  int t = threadIdx.x;
  int base = blockIdx.x*1024 + t*4;
  u32 v[4]; u32 tot = 0;
  for (int k = 0; k < 4; ++k) { v[k] = (base+k < n) ? in[base+k] : 0u; tot += v[k]; }
  lds[t] = tot; __syncthreads();
  for (int o = 1; o < 256; o <<= 1) {
    u32 x = (t >= o) ? lds[t-o] : 0u; __syncthreads();
    lds[t] += x; __syncthreads();
  }
  u32 excl = lds[t] - tot;
  if (t == 255) sums[blockIdx.x] = lds[255];
  u32 run = excl;
  for (int k = 0; k < 4; ++k) { if (base+k < n) out[base+k] = run; run += v[k]; }
}

__global__ void scan_sums(u32* __restrict__ s, int nb) {
  __shared__ u32 lds[256];
  __shared__ u32 carry;
  int t = threadIdx.x;
  if (t == 0) carry = 0;
  __syncthreads();
  for (int base = 0; base < nb; base += 1024) {
    int idx = base + t*4;
    u32 v[4]; u32 tot = 0;
    for (int k = 0; k < 4; ++k) { v[k] = (idx+k < nb) ? s[idx+k] : 0u; tot += v[k]; }
    lds[t] = tot; __syncthreads();
    for (int o = 1; o < 256; o <<= 1) {
      u32 x = (t >= o) ? lds[t-o] : 0u; __syncthreads();
      lds[t] += x; __syncthreads();
    }
    u32 excl = lds[t] - tot;
    u32 ctot = lds[255];
    u32 c = carry;
    __syncthreads();
    u32 run = c + excl;
    for (int k = 0; k < 4; ++k) { if (idx+k < nb) s[idx+k] = run; run += v[k]; }
    if (t == 0) carry = c + ctot;
    __syncthreads();
  }
}

__global__ void scan_add(u32* __restrict__ out, const u32* __restrict__ sums, int n) {
  int base = blockIdx.x*1024 + threadIdx.x*4;
  u32 a = sums[blockIdx.x];
  for (int k = 0; k < 4; ++k) if (base+k < n) out[base+k] += a;
}

// ---------------- radix sort (8-bit LSD, stable) ----------------
__global__ void k_rhist(const u32* __restrict__ keys, u32* __restrict__ hist,
                        int n, int shift, int nb) {
  __shared__ u32 h[256];
  int t = threadIdx.x;
  h[t] = 0; __syncthreads();
  int i = blockIdx.x*256 + t;
  if (i < n) atomicAdd(&h[(keys[i]>>shift)&255u], 1u);
  __syncthreads();
  hist[(u32)t*nb + blockIdx.x] = h[t];
}

__global__ void k_rscat(const u32* __restrict__ keys, const u32* __restrict__ pay,
                        u32* __restrict__ okeys, u32* __restrict__ opay,
                        const u32* __restrict__ hist, int n, int shift, int nb, int haspay) {
  __shared__ u64 ball[4][8];
  __shared__ u64 vmask[4];
  int t = threadIdx.x, w = t>>6, lane = t&63;
  int i = blockIdx.x*256 + t;
  bool valid = i < n;
  u32 k = valid ? keys[i] : 0u;
  u32 d = (k>>shift)&255u;
  for (int bit = 0; bit < 8; ++bit) {
    u64 bm = __ballot(valid && ((d>>bit)&1u));
    if (lane == 0) ball[w][bit] = bm;
  }
  u64 vb = __ballot(valid ? 1 : 0);
  if (lane == 0) vmask[w] = vb;
  __syncthreads();
  if (valid) {
    u32 rank = 0;
    for (int ww = 0; ww < w; ++ww) {
      u64 m = vmask[ww];
      for (int bit = 0; bit < 8; ++bit) { u64 bb = ball[ww][bit]; m &= ((d>>bit)&1u) ? bb : ~bb; }
      rank += (u32)__popcll(m);
    }
    u64 m = vmask[w];
    for (int bit = 0; bit < 8; ++bit) { u64 bb = ball[w][bit]; m &= ((d>>bit)&1u) ? bb : ~bb; }
    rank += (u32)__popcll(m & ((1ull<<lane)-1ull));
    u32 pos = hist[d*(u32)nb + blockIdx.x] + rank;
    okeys[pos] = k;
    if (haspay) opay[pos] = pay[i];
  }
}

// ---------------- pipeline kernels ----------------
__global__ void k_keys(const int* __restrict__ face, u32* __restrict__ keys) {
  int i = blockIdx.x*256 + threadIdx.x;
  if (i >= K3F) return;
  int s = i / FN, f = i - s*FN;
  int v0 = face[f*3 + s];
  int v1 = face[f*3 + (s == 2 ? 0 : s+1)];
  int a = min(v0, v1), b = max(v0, v1);
  u32 key = (u32)a * (u32)VN + (u32)b;   // int32 wraparound, matches jnp
  keys[i] = key ^ 0x80000000u;           // biased: unsigned order == signed order
}

__global__ void k_uflag(const u32* __restrict__ sk, u32* __restrict__ flags) {
  int i = blockIdx.x*256 + threadIdx.x;
  if (i >= K3F) return;
  flags[i] = (i == 0 || sk[i] != sk[i-1]) ? 1u : 0u;
}

__global__ void k_uwrite(const u32* __restrict__ sk, const u32* __restrict__ flags,
                         const u32* __restrict__ rank, u32* __restrict__ ukeys,
                         u32* __restrict__ scal, const int* __restrict__ divp) {
  int i = blockIdx.x*256 + threadIdx.x;
  if (i >= K3F) return;
  if (flags[i]) ukeys[rank[i]] = sk[i];
  if (i == K3F-1) { u32 E = rank[i] + flags[i]; scal[S_E] = E; scal[S_NUM] = E / (u32)divp[0]; }
}

// edge endpoints (output 0) + numpy-wrapped indices + xe gather, fused
__global__ void k_ennode(const u32* __restrict__ ukeys, const u32* __restrict__ scal,
                         const float* __restrict__ x,
                         u32* __restrict__ enidx, float* __restrict__ xe,
                         float* __restrict__ dout) {
  int e = blockIdx.x*256 + threadIdx.x;
  if (e >= (int)scal[S_E]) return;
  int k = (int)(ukeys[e] ^ 0x80000000u);
  long long kk = (long long)k;
  long long qq = (kk - (kk < 0 ? (long long)(VN-1) : 0ll)) / VN; // floor div
  int q = (int)qq;
  int r = (int)(kk - qq * VN);
  dout[2*e]   = (float)q;
  dout[2*e+1] = (float)r;
  u32 i0 = (u32)(q < 0 ? q + VN : q);  // numpy-style negative index wrap
  u32 i1 = (u32)r;
  enidx[2*e]   = i0;
  enidx[2*e+1] = i1;
  for (int c = 0; c < 3; ++c) xe[e*3+c] = 0.5f*(x[i0*3+c] + x[i1*3+c]);
}

__global__ void k_feid(const int* __restrict__ face, const u32* __restrict__ ukeys,
                       const u32* __restrict__ scal, u32* __restrict__ feid) {
  int i = blockIdx.x*256 + threadIdx.x;
  if (i >= K3F) return;
  int s = i / FN, f = i - s*FN;
  int v0 = face[f*3 + s];
  int v1 = face[f*3 + (s == 2 ? 0 : s+1)];
  int a = min(v0, v1), b = max(v0, v1);
  u32 kb = ((u32)a * (u32)VN + (u32)b) ^ 0x80000000u;
  u32 lo = 0, hi = scal[S_E];
  while (lo < hi) { u32 mid = (lo+hi)>>1; if (ukeys[mid] < kb) lo = mid+1; else hi = mid; }
  feid[f*3 + s] = lo;
}

__global__ void k_elist(const u32* __restrict__ feid, const u32* __restrict__ scal,
                        u32* __restrict__ dst, u32* __restrict__ src) {
  int i = blockIdx.x*256 + threadIdx.x;
  if (i >= NEDG) return;
  const int sb[6] = {0,1,1,2,2,0};
  const int db[6] = {1,0,2,1,0,2};
  if (i < 6*FN) {
    int b = i / FN, f = i - b*FN;
    src[i] = feid[f*3 + sb[b]];
    dst[i] = feid[f*3 + db[b]];
  } else {
    int e = i - 6*FN;
    if (e < (int)scal[S_E]) { src[i] = (u32)e; dst[i] = (u32)e; }
    else { src[i] = 0u; dst[i] = PADKEY; }
  }
}

__global__ void k_off(const u32* __restrict__ dsts, const u32* __restrict__ scal,
                      u32* __restrict__ off) {
  int e = blockIdx.x*256 + threadIdx.x;
  if (e > (int)scal[S_E]) return;
  u32 key = (u32)e, lo = 0, hi = NEDG;
  while (lo < hi) { u32 mid = (lo+hi)>>1; if (dsts[mid] < key) lo = mid+1; else hi = mid; }
  off[e] = lo;
}

// pack weights per hidden unit: [h][0..11] = W1s[0..2], W1n[0..2], b1, W2s[0..1], W2n[0..1], pad
__global__ void k_pack(const float* __restrict__ W1s, const float* __restrict__ W1n,
                       const float* __restrict__ b1,
                       const float* __restrict__ W2s, const float* __restrict__ W2n,
                       float* __restrict__ pk) {
  int h = threadIdx.x;
  if (h >= 256) return;
  float* p = pk + h*12;
  p[0] = W1s[h]; p[1] = W1s[256+h]; p[2] = W1s[512+h];
  p[3] = W1n[h]; p[4] = W1n[256+h]; p[5] = W1n[512+h];
  p[6] = b1[h];
  p[7] = W2s[2*h]; p[8] = W2s[2*h+1];
  p[9] = W2n[2*h]; p[10] = W2n[2*h+1];
  p[11] = 0.0f;
}

// fused neighbor-mean + layer1(relu-gsnconv) + projection, thread-per-edge.
// Weight index depends only on the loop counter -> wave-uniform -> s_load on the
// scalar pipe; VALU does ~11 FMA-class ops per hidden unit with no shuffles.
// Arithmetic expression shapes kept identical to v2 (same contraction, same /dg,
// same j=s..t gather order) for bit-exact output.
__global__ void k_l12(const float* __restrict__ xe, const u32* __restrict__ off,
                      const u32* __restrict__ srcs, const u32* __restrict__ scal,
                      const float* __restrict__ pk,
                      float* __restrict__ P, float* __restrict__ Q) {
  int e = blockIdx.x*256 + threadIdx.x;
  if (e >= (int)scal[S_E]) return;
  u32 s = off[e], t = off[e+1];
  float c0 = 0.f, c1 = 0.f, c2 = 0.f;
  for (u32 j = s; j < t; ++j) {               // sequential in original edge order
    u32 u = srcs[j];
    c0 += xe[u*3]; c1 += xe[u*3+1]; c2 += xe[u*3+2];
  }
  float x0 = xe[e*3], x1 = xe[e*3+1], x2 = xe[e*3+2];
  float dg = (float)(t - s);
  float m0 = c0/dg, m1 = c1/dg, m2 = c2/dg;
  float p0 = 0.f, p1 = 0.f, q0 = 0.f, q1 = 0.f;
#pragma unroll 4
  for (int hh = 0; hh < 256; ++hh) {
    const float* w = pk + hh*12;
    float s1 = x0*w[0] + x1*w[1] + x2*w[2];
    float s2 = m0*w[3] + m1*w[4] + m2*w[5];
    float h = fmaxf(s1 + s2 + w[6], 0.0f);
    p0 += h*w[7];  p1 += h*w[8];
    q0 += h*w[9];  q1 += h*w[10];
  }
  P[2*e] = p0; P[2*e+1] = p1; Q[2*e] = q0; Q[2*e+1] = q1;
}

__global__ void k_scores(const float* __restrict__ P, const float* __restrict__ Q,
                         const u32* __restrict__ off, const u32* __restrict__ srcs,
                         const float* __restrict__ b2, const u32* __restrict__ scal,
                         float* __restrict__ Y, u32* __restrict__ ymap) {
  int e = blockIdx.x*256 + threadIdx.x;
  u32 E = scal[S_E];
  if (e >= (int)E) return;
  u32 s = off[e], t = off[e+1];
  float dg = (float)(t - s);
  float a0 = 0.f, a1 = 0.f;
  for (u32 j = s; j < t; ++j) { u32 u = srcs[j]; a0 += Q[2*u]; a1 += Q[2*u+1]; }
  float z0 = P[2*e]   + a0/dg + b2[0];
  float z1 = P[2*e+1] + a1/dg + b2[1];
  float l0 = 1.0f/(1.0f + expf(-z0));
  float l1 = 1.0f/(1.0f + expf(-z1));
  // JAX partitionable threefry: bits(i) = o0^o1 of threefry(key=(0,42), counts=(i>>32, i&...))
  u32 g0b, g1b;
  { u32 o0,o1; tf2x32(0u, 2u*(u32)e,      o0, o1); g0b = o0 ^ o1; }
  { u32 o0,o1; tf2x32(0u, 2u*(u32)e + 1u, o0, o1); g1b = o0 ^ o1; }
  float U0 = __uint_as_float((g0b>>9) | 0x3f800000u) - 1.0f;
  float U1 = __uint_as_float((g1b>>9) | 0x3f800000u) - 1.0f;
  float g0 = -logf(-logf(U0 + 1e-20f) + 1e-20f);
  float g1 = -logf(-logf(U1 + 1e-20f) + 1e-20f);
  float A0 = (l0 + g0)/0.1f;
  float A1 = (l1 + g1)/0.1f;
  float mx = fmaxf(A0, A1);
  float e0 = expf(A0-mx), e1 = expf(A1-mx);
  float y = e0/(e0+e1);
  Y[e] = y;
  ymap[e] = __float_as_uint(y) | 0x80000000u;   // monotone map (y >= 0)
}

// ---------------- exact top-k threshold (byte-wise descent) ----------------
__global__ void k_tkinit(u32* __restrict__ scal, u32* __restrict__ hist) {
  int t = threadIdx.x;
  if (t < 256) hist[t] = 0u;
  if (t == 0) { scal[S_PFX] = 0u; scal[S_KREM] = scal[S_NUM]; }
}

// two-level histogram: LDS per block, then one global atomic per non-zero bucket.
__global__ void k_tkhist(const u32* __restrict__ ymap, const u32* __restrict__ scal,
                         u32* __restrict__ hist, int byte) {
  __shared__ u32 h[256];
  int t = threadIdx.x;
  h[t] = 0u; __syncthreads();
  int E = (int)scal[S_E];
  u32 pfx = scal[S_PFX];
  int base = blockIdx.x*1024;
  for (int k = 0; k < 4; ++k) {
    int e = base + k*256 + t;
    if (e < E) {
      u32 u = ymap[e];
      bool match = (byte == 3) || ((u >> ((byte+1)*8)) == pfx);
      if (match) atomicAdd(&h[(u >> (byte*8)) & 255u], 1u);
    }
  }
  __syncthreads();
  u32 c = h[t];
  if (c) atomicAdd(&hist[t], c);
}

__global__ void k_tksel(u32* __restrict__ scal, u32* __restrict__ hist, int byte) {
  if (threadIdx.x != 0 || blockIdx.x != 0) return;
  u32 krem = scal[S_KREM], pfx = scal[S_PFX];
  u32 chosen = 0;
  for (int b = 255; b >= 0; --b) {
    u32 c = hist[b];
    if (krem <= c) { chosen = (u32)b; break; }
    krem -= c;
  }
  pfx = (pfx << 8) | chosen;
  scal[S_PFX] = pfx; scal[S_KREM] = krem;
  if (byte == 0) { scal[S_TU] = pfx; scal[S_R] = krem; }
  for (int i = 0; i < 256; ++i) hist[i] = 0u;
}

__global__ void k_tflag(const u32* __restrict__ ymap, const u32* __restrict__ scal,
                        u32* __restrict__ tf) {
  int e = blockIdx.x*256 + threadIdx.x;
  if (e >= EMAX) return;
  tf[e] = (e < (int)scal[S_E] && ymap[e] == scal[S_TU]) ? 1u : 0u;
}

__global__ void k_sel(const u32* __restrict__ ymap, const u32* __restrict__ tier,
                      const u32* __restrict__ scal, u32* __restrict__ sel) {
  int e = blockIdx.x*256 + threadIdx.x;
  if (e >= EMAX) return;
  u32 v = 0;
  if (e < (int)scal[S_E]) {
    u32 u = ymap[e];
    v = (u > scal[S_TU]) || (u == scal[S_TU] && tier[e] < scal[S_R]);
  }
  sel[e] = v ? 1u : 0u;
}

// ---------------- mesh collapse ----------------
__global__ void k_cat(const u32* __restrict__ feid, const u32* __restrict__ sel,
                      u32* __restrict__ cat) {
  int f = blockIdx.x*256 + threadIdx.x;
  if (f >= FN) return;
  u32 m0 = sel[feid[f*3]], m1 = sel[feid[f*3+1]], m2 = sel[feid[f*3+2]];
  u32 pen = m0 + m1 + m2;
  u32 psi = m1 + 2u*m2;
  u32 c = (pen == 0) ? 0u : (pen == 1) ? (1u+psi) : (pen == 2) ? (3u+psi) : 7u;
  cat[f] = c;
}

__global__ void k_cathist(const u32* __restrict__ cat, u32* __restrict__ ch) {
  __shared__ u32 h[8];
  int t = threadIdx.x;
  if (t < 8) h[t] = 0u;
  __syncthreads();
  int base = blockIdx.x*1024 + t*4;
  for (int k = 0; k < 4; ++k) if (base+k < FN) atomicAdd(&h[cat[base+k]], 1u);
  __syncthreads();
  if (t < 8) ch[(u32)t*NBC + blockIdx.x] = h[t];
}

__global__ void k_catoff(u32* __restrict__ ch, u32* __restrict__ scal) {
  if (threadIdx.x || blockIdx.x) return;
  u32 tot[8];
  for (int c = 0; c < 8; ++c) { u32 s = 0; for (int b = 0; b < NBC; ++b) s += ch[c*NBC+b]; tot[c] = s; }
  u32 run = 0;
  for (int i = 0; i < 8*NBC; ++i) { u32 v = ch[i]; ch[i] = run; run += v; }
  u32 n0 = tot[0], n1 = tot[1]+tot[2]+tot[3], n2 = tot[4]+tot[5]+tot[6], n3 = tot[7];
  u32 NF = n0 + 2u*n1 + 3u*n2 + 4u*n3;
  u32 E = scal[S_E], num = scal[S_NUM];
  u32 NEn = (u32)VN + num + 3u*NF;
  scal[S_NF] = NF; scal[S_NEN] = NEn;
  scal[S_O1] = 2u*E;
  scal[S_O2] = 2u*E + 3u*NF;
  scal[S_O3] = 2u*E + 3u*NF + 2u*NEn;
  u32 RS[8] = {0u, n0,n0,n0, n0+2u*n1, n0+2u*n1, n0+2u*n1, n0+2u*n1+3u*n2};
  u32 GS[8] = {0u, n1,n1,n1, n2,n2,n2, n3};
  u32 GP[8] = {0u, n0,n0,n0, n0+n1, n0+n1, n0+n1, n0+n1+n2};
  for (int i = 0; i < 8; ++i) { scal[S_RS+i] = RS[i]; scal[S_GS+i] = GS[i]; scal[S_GP+i] = GP[i]; }
}

__global__ void k_catrank(const u32* __restrict__ cat, const u32* __restrict__ ch,
                          u32* __restrict__ cr) {
  __shared__ u32 lds[256];
  int t = threadIdx.x;
  int base = blockIdx.x*1024 + t*4;
  u32 cc[4], loc[4];
  u32 cnt[8] = {0,0,0,0,0,0,0,0};
  for (int k = 0; k < 4; ++k) {
    int i = base + k;
    if (i < FN) { u32 c = cat[i]; cc[k] = c; loc[k] = cnt[c]++; }
    else cc[k] = 8u;
  }
  u32 tb[8];
  for (int c = 0; c < 8; ++c) {
    lds[t] = cnt[c]; __syncthreads();
    for (int o = 1; o < 256; o <<= 1) {
      u32 x = (t >= o) ? lds[t-o] : 0u; __syncthreads();
      lds[t] += x; __syncthreads();
    }
    tb[c] = lds[t] - cnt[c];
    __syncthreads();
  }
  for (int k = 0; k < 4; ++k) {
    int i = base + k;
    if (i < FN) { u32 c = cc[k]; cr[i] = ch[c*NBC + blockIdx.x] + tb[c] + loc[k]; }
  }
}

__global__ void k_wfaces(const int* __restrict__ face, const u32* __restrict__ cat,
                         const u32* __restrict__ cr, const u32* __restrict__ feid,
                         const u32* __restrict__ selr, const u32* __restrict__ scal,
                         int* __restrict__ nfi, float* __restrict__ dout) {
  int f = blockIdx.x*256 + threadIdx.x;
  if (f >= FN) return;
  const int nfc[8] = {1,2,2,2,3,3,3,4};
  const int tri[8][4][3] = {
    {{0,2,4},{0,0,0},{0,0,0},{0,0,0}},
    {{0,1,4},{1,2,4},{0,0,0},{0,0,0}},
    {{2,3,0},{3,4,0},{0,0,0},{0,0,0}},
    {{4,5,2},{5,0,2},{0,0,0},{0,0,0}},
    {{0,1,4},{1,2,3},{1,3,4},{0,0,0}},
    {{4,5,2},{5,0,1},{5,1,2},{0,0,0}},
    {{2,3,0},{3,4,5},{3,5,0},{0,0,0}},
    {{0,1,5},{1,2,3},{1,3,5},{3,4,5}}};
  u32 c = cat[f];
  int cv[6];
  cv[0] = face[f*3];   cv[2] = face[f*3+1]; cv[4] = face[f*3+2];
  cv[1] = VN + (int)selr[feid[f*3]];
  cv[3] = VN + (int)selr[feid[f*3+1]];
  cv[5] = VN + (int)selr[feid[f*3+2]];
  u32 g  = cr[f] - scal[S_GP + c];
  u32 o1 = scal[S_O1];
  for (int j = 0; j < nfc[c]; ++j) {
    u32 row = scal[S_RS + c] + (u32)j*scal[S_GS + c] + g;
    for (int m = 0; m < 3; ++m) {
      int v = cv[tri[c][j][m]];
      nfi[row*3 + m] = v;
      dout[o1 + row*3 + m] = (float)v;
    }
  }
}

__global__ void k_wne(const int* __restrict__ nfi, const u32* __restrict__ scal,
                      float* __restrict__ dout) {
  int i = blockIdx.x*256 + threadIdx.x;
  u32 NEn = scal[S_NEN];
  if (i >= (int)NEn) return;
  u32 NF = scal[S_NF];
  u32 Vp = (u32)VN + scal[S_NUM];
  u32 o2 = scal[S_O2];
  int a, b;
  if ((u32)i < Vp) { a = i; b = i; }
  else {
    u32 j = (u32)i - Vp;
    u32 blk = j / NF, r = j - blk*NF;
    int i0 = (blk == 0) ? 0 : (blk == 1) ? 1 : 2;
    int i1 = (blk == 0) ? 1 : (blk == 1) ? 2 : 0;
    a = nfi[r*3 + i0]; b = nfi[r*3 + i1];
  }
  dout[o2 + i] = (float)a;
  dout[o2 + NEn + i] = (float)b;
}

__global__ void k_wmask(const u32* __restrict__ sel, const float* __restrict__ Y,
                        const u32* __restrict__ scal, float* __restrict__ dout) {
  int e = blockIdx.x*256 + threadIdx.x;
  if (e >= (int)scal[S_E]) return;
  float y = Y[e];
  float yh = sel[e] ? 1.0f : 0.0f;
  dout[scal[S_O3] + e] = (yh - y) + y;   // straight-through value
}

// ---------------- host-side drivers ----------------
static void run_scan(u32* in, u32* out, u32* sums, int n, hipStream_t st) {
  int nb = (n + 1023) / 1024;
  scan_blocks<<<nb, 256, 0, st>>>(in, out, sums, n);
  scan_sums<<<1, 256, 0, st>>>(sums, nb);
  scan_add<<<nb, 256, 0, st>>>(out, sums, n);
}

static void radix_pass(u32* kin, u32* pin, u32* kout, u32* pout, u32* hist, u32* sums,
                       int n, int nb, int shift, bool haspay, hipStream_t st) {
  k_rhist<<<nb, 256, 0, st>>>(kin, hist, n, shift, nb);
  run_scan(hist, hist, sums, nb*256, st);
  k_rscat<<<nb, 256, 0, st>>>(kin, pin, kout, pout, hist, n, shift, nb, haspay ? 1 : 0);
}

extern "C" void kernel_launch(void* const* d_in, const int* in_sizes, int n_in,
                              void* d_out, int out_size, void* d_ws, size_t ws_size,
                              hipStream_t stream) {
  const float* x    = (const float*)d_in[0];
  const int*   face = (const int*)d_in[1];
  const int*   divp = (const int*)d_in[4];
  const float* W1s  = (const float*)d_in[5];
  const float* W1n  = (const float*)d_in[6];
  const float* b1   = (const float*)d_in[7];
  const float* W2s  = (const float*)d_in[8];
  const float* W2n  = (const float*)d_in[9];
  const float* b2   = (const float*)d_in[10];
  float* out = (float*)d_out;
  u32* W = (u32*)d_ws;

  u32 *A = W+W_A, *B = W+W_B, *FL = W+W_FLAGS, *RK = W+W_RANKU, *UK = W+W_UKEYS;
  u32 *HIST = W+W_HIST, *SUMS = W+W_SUMS, *SCAL = W+W_SCAL;

  // 0) pack weights (independent of everything else)
  k_pack<<<1, 256, 0, stream>>>(W1s, W1n, b1, W2s, W2n, (float*)(W+W_PK));

  // 1) keys + sort + unique
  k_keys<<<NB1, 256, 0, stream>>>(face, A);
  radix_pass(A, nullptr, B, nullptr, HIST, SUMS, K3F, NB1,  0, false, stream);
  radix_pass(B, nullptr, A, nullptr, HIST, SUMS, K3F, NB1,  8, false, stream);
  radix_pass(A, nullptr, B, nullptr, HIST, SUMS, K3F, NB1, 16, false, stream);
  radix_pass(B, nullptr, A, nullptr, HIST, SUMS, K3F, NB1, 24, false, stream);
  k_uflag<<<NB1, 256, 0, stream>>>(A, FL);
  run_scan(FL, RK, SUMS, K3F, stream);
  k_uwrite<<<NB1, 256, 0, stream>>>(A, FL, RK, UK, SCAL, divp);

  // 2) edge nodes (+xe fused), feid
  k_ennode<<<NB1, 256, 0, stream>>>(UK, SCAL, x, W+W_ENIDX, (float*)(W+W_XE), out);
  k_feid<<<NB1, 256, 0, stream>>>(face, UK, SCAL, W+W_FEID);

  // 3) directed edge list, stable sort by dst -> CSR
  k_elist<<<NB2, 256, 0, stream>>>(W+W_FEID, SCAL, W+W_DSTA, W+W_SRCA);
  radix_pass(W+W_DSTA, W+W_SRCA, W+W_DSTB, W+W_SRCB, HIST, SUMS, NEDG, NB2,  0, true, stream);
  radix_pass(W+W_DSTB, W+W_SRCB, W+W_DSTA, W+W_SRCA, HIST, SUMS, NEDG, NB2,  8, true, stream);
  radix_pass(W+W_DSTA, W+W_SRCA, W+W_DSTB, W+W_SRCB, HIST, SUMS, NEDG, NB2, 16, true, stream);
  k_off<<<1173, 256, 0, stream>>>(W+W_DSTB, SCAL, W+W_OFF);

  // 4) GSN conv layers (fused agg + both matmuls, thread-per-edge, scalar weights)
  k_l12<<<NB1, 256, 0, stream>>>((float*)(W+W_XE), W+W_OFF, W+W_SRCB, SCAL,
                                 (float*)(W+W_PK), (float*)(W+W_P), (float*)(W+W_Q));
  k_scores<<<NB1, 256, 0, stream>>>((float*)(W+W_P), (float*)(W+W_Q), W+W_OFF, W+W_SRCB,
                                    b2, SCAL, (float*)(W+W_Y), W+W_YMAP);

  // 5) exact top-k (byte descent) + tie-stable selection
  k_tkinit<<<1, 256, 0, stream>>>(SCAL, HIST);
  for (int byte = 3; byte >= 0; --byte) {
    k_tkhist<<<NBH, 256, 0, stream>>>(W+W_YMAP, SCAL, HIST, byte);
    k_tksel<<<1, 1, 0, stream>>>(SCAL, HIST, byte);
  }
  k_tflag<<<NB1, 256, 0, stream>>>(W+W_YMAP, SCAL, W+W_TFLAG);
  run_scan(W+W_TFLAG, W+W_TIER, SUMS, EMAX, stream);
  k_sel<<<NB1, 256, 0, stream>>>(W+W_YMAP, W+W_TIER, SCAL, W+W_SEL);
  run_scan(W+W_SEL, W+W_SELR, SUMS, EMAX, stream);

  // 6) mesh collapse
  k_cat<<<391, 256, 0, stream>>>(W+W_FEID, W+W_SEL, W+W_CAT);
  k_cathist<<<NBC, 256, 0, stream>>>(W+W_CAT, W+W_CATH);
  k_catoff<<<1, 1, 0, stream>>>(W+W_CATH, SCAL);
  k_catrank<<<NBC, 256, 0, stream>>>(W+W_CAT, W+W_CATH, W+W_CATR);
  k_wfaces<<<391, 256, 0, stream>>>(face, W+W_CAT, W+W_CATR, W+W_FEID, W+W_SELR, SCAL,
                                    (int*)(W+W_NFI), out);
  k_wne<<<5118, 256, 0, stream>>>((int*)(W+W_NFI), SCAL, out);
  k_wmask<<<NB1, 256, 0, stream>>>(W+W_SEL, (float*)(W+W_Y), SCAL, out);
}

// Round 4
// 381.858 us; speedup vs baseline: 8.7571x; 1.3166x over previous
//
#include <hip/hip_runtime.h>
#include <stdint.h>

typedef uint32_t u32;
typedef uint64_t u64;

#define VN 50000
#define FN 100000
#define K3F 300000
#define EMAX 300000
#define NB1 1172          // ceil(300000/256)
#define NBC 98            // ceil(100000/1024)
#define NBH 293           // ceil(300000/1024)

// ---------------- workspace layout (u32 units) ----------------
#define W_A      0u        // 300000 keys ping
#define W_B      300000u   // 300000 keys pong
#define W_PA     600000u   // 300000 payload ping
#define W_PB     900000u   // 300000 payload pong
#define W_FLAGS  1200000u  // 300000
#define W_RANKU  1500000u  // 300000
#define W_UKEYS  1800000u  // 300000
#define W_SEGOFF 2100000u  // 300001
#define W_FEID   2400004u  // 300000
#define W_XE     2700004u  // 900000 f32
#define W_PK     3600004u  // 3072 f32 packed weights
#define W_P      3700004u  // 600000 f32
#define W_Q      4300004u  // 600000 f32
#define W_Y      4900004u  // 300000 f32
#define W_YMAP   5200004u
#define W_TFLAG  5500004u
#define W_TIER   5800004u
#define W_SEL    6100004u
#define W_SELR   6400004u
#define W_CAT    6700004u  // 100000
#define W_CATR   6800004u  // 100000
#define W_NFI    6900004u  // 1200000 int (new faces)
#define W_HIST   8100004u  // 300032
#define W_SUMS   8400100u  // 4096
#define W_CATH   8404196u  // 1024
#define W_SCAL   8405220u  // 64

#define S_E 0
#define S_NUM 1
#define S_PFX 2
#define S_KREM 3
#define S_TU 4
#define S_R 5
#define S_NF 6
#define S_NEN 7
#define S_O1 8
#define S_O2 9
#define S_O3 10
#define S_RS 16
#define S_GS 24
#define S_GP 32

// ---------------- threefry2x32, key = (0, 42) ----------------
__device__ __forceinline__ void tf2x32(u32 x0, u32 x1, u32& o0, u32& o1) {
  const u32 ks0 = 0u, ks1 = 42u, ks2 = 0x1BD11BDAu ^ 0u ^ 42u;
  x0 += ks0; x1 += ks1;
#define TFR(r) { x0 += x1; x1 = (x1<<(r))|(x1>>(32-(r))); x1 ^= x0; }
  TFR(13) TFR(15) TFR(26) TFR(6)   x0 += ks1; x1 += ks2 + 1u;
  TFR(17) TFR(29) TFR(16) TFR(24)  x0 += ks2; x1 += ks0 + 2u;
  TFR(13) TFR(15) TFR(26) TFR(6)   x0 += ks0; x1 += ks1 + 3u;
  TFR(17) TFR(29) TFR(16) TFR(24)  x0 += ks1; x1 += ks2 + 4u;
  TFR(13) TFR(15) TFR(26) TFR(6)   x0 += ks2; x1 += ks0 + 5u;
#undef TFR
  o0 = x0; o1 = x1;
}

// ---------------- generic exclusive scan (u32) ----------------
__global__ void scan_blocks(const u32* __restrict__ in, u32* __restrict__ out,
                            u32* __restrict__ sums, int n) {
  __shared__ u32 lds[256];
  int t = threadIdx.x;
  int base = blockIdx.x*1024 + t*4;
  u32 v[4]; u32 tot = 0;
  for (int k = 0; k < 4; ++k) { v[k] = (base+k < n) ? in[base+k] : 0u; tot += v[k]; }
  lds[t] = tot; __syncthreads();
  for (int o = 1; o < 256; o <<= 1) {
    u32 x = (t >= o) ? lds[t-o] : 0u; __syncthreads();
    lds[t] += x; __syncthreads();
  }
  u32 excl = lds[t] - tot;
  if (t == 255) sums[blockIdx.x] = lds[255];
  u32 run = excl;
  for (int k = 0; k < 4; ++k) { if (base+k < n) out[base+k] = run; run += v[k]; }
}

__global__ void scan_sums(u32* __restrict__ s, int nb) {
  __shared__ u32 lds[256];
  __shared__ u32 carry;
  int t = threadIdx.x;
  if (t == 0) carry = 0;
  __syncthreads();
  for (int base = 0; base < nb; base += 1024) {
    int idx = base + t*4;
    u32 v[4]; u32 tot = 0;
    for (int k = 0; k < 4; ++k) { v[k] = (idx+k < nb) ? s[idx+k] : 0u; tot += v[k]; }
    lds[t] = tot; __syncthreads();
    for (int o = 1; o < 256; o <<= 1) {
      u32 x = (t >= o) ? lds[t-o] : 0u; __syncthreads();
      lds[t] += x; __syncthreads();
    }
    u32 excl = lds[t] - tot;
    u32 ctot = lds[255];
    u32 c = carry;
    __syncthreads();
    u32 run = c + excl;
    for (int k = 0; k < 4; ++k) { if (idx+k < nb) s[idx+k] = run; run += v[k]; }
    if (t == 0) carry = c + ctot;
    __syncthreads();
  }
}

__global__ void scan_add(u32* __restrict__ out, const u32* __restrict__ sums, int n) {
  int base = blockIdx.x*1024 + threadIdx.x*4;
  u32 a = sums[blockIdx.x];
  for (int k = 0; k < 4; ++k) if (base+k < n) out[base+k] += a;
}

// ---------------- radix sort (8-bit LSD, stable) ----------------
__global__ void k_rhist(const u32* __restrict__ keys, u32* __restrict__ hist,
                        int n, int shift, int nb) {
  __shared__ u32 h[256];
  int t = threadIdx.x;
  h[t] = 0; __syncthreads();
  int i = blockIdx.x*256 + t;
  if (i < n) atomicAdd(&h[(keys[i]>>shift)&255u], 1u);
  __syncthreads();
  hist[(u32)t*nb + blockIdx.x] = h[t];
}

__global__ void k_rscat(const u32* __restrict__ keys, const u32* __restrict__ pay,
                        u32* __restrict__ okeys, u32* __restrict__ opay,
                        const u32* __restrict__ hist, int n, int shift, int nb, int haspay) {
  __shared__ u64 ball[4][8];
  __shared__ u64 vmask[4];
  int t = threadIdx.x, w = t>>6, lane = t&63;
  int i = blockIdx.x*256 + t;
  bool valid = i < n;
  u32 k = valid ? keys[i] : 0u;
  u32 d = (k>>shift)&255u;
  for (int bit = 0; bit < 8; ++bit) {
    u64 bm = __ballot(valid && ((d>>bit)&1u));
    if (lane == 0) ball[w][bit] = bm;
  }
  u64 vb = __ballot(valid ? 1 : 0);
  if (lane == 0) vmask[w] = vb;
  __syncthreads();
  if (valid) {
    u32 rank = 0;
    for (int ww = 0; ww < w; ++ww) {
      u64 m = vmask[ww];
      for (int bit = 0; bit < 8; ++bit) { u64 bb = ball[ww][bit]; m &= ((d>>bit)&1u) ? bb : ~bb; }
      rank += (u32)__popcll(m);
    }
    u64 m = vmask[w];
    for (int bit = 0; bit < 8; ++bit) { u64 bb = ball[w][bit]; m &= ((d>>bit)&1u) ? bb : ~bb; }
    rank += (u32)__popcll(m & ((1ull<<lane)-1ull));
    u32 pos = hist[d*(u32)nb + blockIdx.x] + rank;
    okeys[pos] = k;
    if (haspay) opay[pos] = pay[i];
  }
}

// ---------------- pipeline kernels ----------------
__global__ void k_keys(const int* __restrict__ face, u32* __restrict__ keys,
                       u32* __restrict__ pay) {
  int i = blockIdx.x*256 + threadIdx.x;
  if (i >= K3F) return;
  int s = i / FN, f = i - s*FN;
  int v0 = face[f*3 + s];
  int v1 = face[f*3 + (s == 2 ? 0 : s+1)];
  int a = min(v0, v1), b = max(v0, v1);
  u32 key = (u32)a * (u32)VN + (u32)b;   // int32 wraparound, matches jnp
  keys[i] = key ^ 0x80000000u;           // biased: unsigned order == signed order
  pay[i] = (u32)i;                       // original index = s*FN + f
}

__global__ void k_uflag(const u32* __restrict__ sk, u32* __restrict__ flags) {
  int i = blockIdx.x*256 + threadIdx.x;
  if (i >= K3F) return;
  flags[i] = (i == 0 || sk[i] != sk[i-1]) ? 1u : 0u;
}

// unique keys + segment offsets + feid scatter, fused.
// unique-id at sorted position p: RK[p] - 1 + flags[p]; feid[f*3+s] = id for i=pay[p]=s*FN+f
__global__ void k_uwrite(const u32* __restrict__ sk, const u32* __restrict__ flags,
                         const u32* __restrict__ rank, const u32* __restrict__ pay,
                         u32* __restrict__ ukeys, u32* __restrict__ segoff,
                         u32* __restrict__ feid,
                         u32* __restrict__ scal, const int* __restrict__ divp) {
  int p = blockIdx.x*256 + threadIdx.x;
  if (p >= K3F) return;
  u32 fl = flags[p], rk = rank[p];
  if (fl) { ukeys[rk] = sk[p]; segoff[rk] = (u32)p; }
  u32 id = rk - 1u + fl;
  u32 i = pay[p];
  u32 s = i / FN, f = i - s*FN;
  feid[f*3 + s] = id;
  if (p == K3F-1) {
    u32 E = rk + fl;
    scal[S_E] = E; scal[S_NUM] = E / (u32)divp[0];
    segoff[E] = (u32)K3F;
  }
}

// edge endpoints (output 0) + xe gather, fused
__global__ void k_ennode(const u32* __restrict__ ukeys, const u32* __restrict__ scal,
                         const float* __restrict__ x,
                         float* __restrict__ xe, float* __restrict__ dout) {
  int e = blockIdx.x*256 + threadIdx.x;
  if (e >= (int)scal[S_E]) return;
  int k = (int)(ukeys[e] ^ 0x80000000u);
  long long kk = (long long)k;
  long long qq = (kk - (kk < 0 ? (long long)(VN-1) : 0ll)) / VN; // floor div
  int q = (int)qq;
  int r = (int)(kk - qq * VN);
  dout[2*e]   = (float)q;
  dout[2*e+1] = (float)r;
  u32 i0 = (u32)(q < 0 ? q + VN : q);  // numpy-style negative index wrap
  u32 i1 = (u32)r;
  for (int c = 0; c < 3; ++c) xe[e*3+c] = 0.5f*(x[i0*3+c] + x[i1*3+c]);
}

// pack weights per hidden unit: [h][0..11] = W1s[0..2], W1n[0..2], b1, W2s[0..1], W2n[0..1], pad
__global__ void k_pack(const float* __restrict__ W1s, const float* __restrict__ W1n,
                       const float* __restrict__ b1,
                       const float* __restrict__ W2s, const float* __restrict__ W2n,
                       float* __restrict__ pk) {
  int h = threadIdx.x;
  if (h >= 256) return;
  float* p = pk + h*12;
  p[0] = W1s[h]; p[1] = W1s[256+h]; p[2] = W1s[512+h];
  p[3] = W1n[h]; p[4] = W1n[256+h]; p[5] = W1n[512+h];
  p[6] = b1[h];
  p[7] = W2s[2*h]; p[8] = W2s[2*h+1];
  p[9] = W2n[2*h]; p[10] = W2n[2*h+1];
  p[11] = 0.0f;
}

// Neighbor aggregation direct from key-sort segments — replaces the 900k edge-list
// sort + CSR. Reference order (blocks b=0..5 then self-loop, f ascending within b)
// == segment order restricted to slot==dstslot[b] (payload i=s*FN+f is s-major,
// stable sort keeps i ascending within a segment). Bit-exact vs the CSR version.
__device__ __forceinline__ void agg_neighbors(int e, u32 st, u32 en,
                                              const u32* __restrict__ pay,
                                              const u32* __restrict__ feid,
                                              const float* __restrict__ v, int stride,
                                              float* acc0, float* acc1, float* acc2) {
  const int sslot[6] = {0,1,1,2,2,0};
  const int dslot[6] = {1,0,2,1,0,2};
  float c0 = 0.f, c1 = 0.f, c2 = 0.f;
  for (int b = 0; b < 6; ++b) {
    int j = dslot[b], isl = sslot[b];
    for (u32 p = st; p < en; ++p) {
      u32 i = pay[p];
      u32 s = i / FN;
      if ((int)s == j) {
        u32 f = i - s*FN;
        u32 u = feid[f*3 + isl];
        c0 += v[u*stride]; c1 += v[u*stride+1]; if (stride == 3) c2 += v[u*stride+2];
      }
    }
  }
  c0 += v[e*stride]; c1 += v[e*stride+1]; if (stride == 3) c2 += v[e*stride+2];
  *acc0 = c0; *acc1 = c1; *acc2 = c2;
}

// fused neighbor-mean + layer1(relu-gsnconv) + projection, thread-per-edge.
// Weight index depends only on the loop counter -> wave-uniform -> scalar loads.
__global__ void k_l12(const float* __restrict__ xe, const u32* __restrict__ segoff,
                      const u32* __restrict__ pay, const u32* __restrict__ feid,
                      const u32* __restrict__ scal, const float* __restrict__ pk,
                      float* __restrict__ P, float* __restrict__ Q) {
  int e = blockIdx.x*256 + threadIdx.x;
  if (e >= (int)scal[S_E]) return;
  u32 st = segoff[e], en = segoff[e+1];
  float c0, c1, c2;
  agg_neighbors(e, st, en, pay, feid, xe, 3, &c0, &c1, &c2);
  float x0 = xe[e*3], x1 = xe[e*3+1], x2 = xe[e*3+2];
  float dg = (float)(2u*(en - st) + 1u);
  float m0 = c0/dg, m1 = c1/dg, m2 = c2/dg;
  float p0 = 0.f, p1 = 0.f, q0 = 0.f, q1 = 0.f;
#pragma unroll 8
  for (int hh = 0; hh < 256; ++hh) {
    const float* w = pk + hh*12;
    float s1 = x0*w[0] + x1*w[1] + x2*w[2];
    float s2 = m0*w[3] + m1*w[4] + m2*w[5];
    float h = fmaxf(s1 + s2 + w[6], 0.0f);
    p0 += h*w[7];  p1 += h*w[8];
    q0 += h*w[9];  q1 += h*w[10];
  }
  P[2*e] = p0; P[2*e+1] = p1; Q[2*e] = q0; Q[2*e+1] = q1;
}

__global__ void k_scores(const float* __restrict__ P, const float* __restrict__ Q,
                         const u32* __restrict__ segoff, const u32* __restrict__ pay,
                         const u32* __restrict__ feid,
                         const float* __restrict__ b2, const u32* __restrict__ scal,
                         float* __restrict__ Y, u32* __restrict__ ymap) {
  int e = blockIdx.x*256 + threadIdx.x;
  u32 E = scal[S_E];
  if (e >= (int)E) return;
  u32 st = segoff[e], en = segoff[e+1];
  float a0, a1, dummy;
  agg_neighbors(e, st, en, pay, feid, Q, 2, &a0, &a1, &dummy);
  float dg = (float)(2u*(en - st) + 1u);
  float z0 = P[2*e]   + a0/dg + b2[0];
  float z1 = P[2*e+1] + a1/dg + b2[1];
  float l0 = 1.0f/(1.0f + expf(-z0));
  float l1 = 1.0f/(1.0f + expf(-z1));
  // JAX partitionable threefry: bits(i) = o0^o1 of threefry(key=(0,42), counts)
  u32 g0b, g1b;
  { u32 o0,o1; tf2x32(0u, 2u*(u32)e,      o0, o1); g0b = o0 ^ o1; }
  { u32 o0,o1; tf2x32(0u, 2u*(u32)e + 1u, o0, o1); g1b = o0 ^ o1; }
  float U0 = __uint_as_float((g0b>>9) | 0x3f800000u) - 1.0f;
  float U1 = __uint_as_float((g1b>>9) | 0x3f800000u) - 1.0f;
  float g0 = -logf(-logf(U0 + 1e-20f) + 1e-20f);
  float g1 = -logf(-logf(U1 + 1e-20f) + 1e-20f);
  float A0 = (l0 + g0)/0.1f;
  float A1 = (l1 + g1)/0.1f;
  float mx = fmaxf(A0, A1);
  float e0 = expf(A0-mx), e1 = expf(A1-mx);
  float y = e0/(e0+e1);
  Y[e] = y;
  ymap[e] = __float_as_uint(y) | 0x80000000u;   // monotone map (y >= 0)
}

// ---------------- exact top-k threshold (byte-wise descent) ----------------
__global__ void k_tkinit(u32* __restrict__ scal, u32* __restrict__ hist) {
  int t = threadIdx.x;
  if (t < 256) hist[t] = 0u;
  if (t == 0) { scal[S_PFX] = 0u; scal[S_KREM] = scal[S_NUM]; }
}

// two-level histogram: LDS per block, then one global atomic per non-zero bucket.
__global__ void k_tkhist(const u32* __restrict__ ymap, const u32* __restrict__ scal,
                         u32* __restrict__ hist, int byte) {
  __shared__ u32 h[256];
  int t = threadIdx.x;
  h[t] = 0u; __syncthreads();
  int E = (int)scal[S_E];
  u32 pfx = scal[S_PFX];
  int base = blockIdx.x*1024;
  for (int k = 0; k < 4; ++k) {
    int e = base + k*256 + t;
    if (e < E) {
      u32 u = ymap[e];
      bool match = (byte == 3) || ((u >> ((byte+1)*8)) == pfx);
      if (match) atomicAdd(&h[(u >> (byte*8)) & 255u], 1u);
    }
  }
  __syncthreads();
  u32 c = h[t];
  if (c) atomicAdd(&hist[t], c);
}

__global__ void k_tksel(u32* __restrict__ scal, u32* __restrict__ hist, int byte) {
  if (threadIdx.x != 0 || blockIdx.x != 0) return;
  u32 krem = scal[S_KREM], pfx = scal[S_PFX];
  u32 chosen = 0;
  for (int b = 255; b >= 0; --b) {
    u32 c = hist[b];
    if (krem <= c) { chosen = (u32)b; break; }
    krem -= c;
  }
  pfx = (pfx << 8) | chosen;
  scal[S_PFX] = pfx; scal[S_KREM] = krem;
  if (byte == 0) { scal[S_TU] = pfx; scal[S_R] = krem; }
  for (int i = 0; i < 256; ++i) hist[i] = 0u;
}

__global__ void k_tflag(const u32* __restrict__ ymap, const u32* __restrict__ scal,
                        u32* __restrict__ tf) {
  int e = blockIdx.x*256 + threadIdx.x;
  if (e >= EMAX) return;
  tf[e] = (e < (int)scal[S_E] && ymap[e] == scal[S_TU]) ? 1u : 0u;
}

__global__ void k_sel(const u32* __restrict__ ymap, const u32* __restrict__ tier,
                      const u32* __restrict__ scal, u32* __restrict__ sel) {
  int e = blockIdx.x*256 + threadIdx.x;
  if (e >= EMAX) return;
  u32 v = 0;
  if (e < (int)scal[S_E]) {
    u32 u = ymap[e];
    v = (u > scal[S_TU]) || (u == scal[S_TU] && tier[e] < scal[S_R]);
  }
  sel[e] = v ? 1u : 0u;
}

// ---------------- mesh collapse ----------------
__global__ void k_cat(const u32* __restrict__ feid, const u32* __restrict__ sel,
                      u32* __restrict__ cat) {
  int f = blockIdx.x*256 + threadIdx.x;
  if (f >= FN) return;
  u32 m0 = sel[feid[f*3]], m1 = sel[feid[f*3+1]], m2 = sel[feid[f*3+2]];
  u32 pen = m0 + m1 + m2;
  u32 psi = m1 + 2u*m2;
  u32 c = (pen == 0) ? 0u : (pen == 1) ? (1u+psi) : (pen == 2) ? (3u+psi) : 7u;
  cat[f] = c;
}

__global__ void k_cathist(const u32* __restrict__ cat, u32* __restrict__ ch) {
  __shared__ u32 h[8];
  int t = threadIdx.x;
  if (t < 8) h[t] = 0u;
  __syncthreads();
  int base = blockIdx.x*1024 + t*4;
  for (int k = 0; k < 4; ++k) if (base+k < FN) atomicAdd(&h[cat[base+k]], 1u);
  __syncthreads();
  if (t < 8) ch[(u32)t*NBC + blockIdx.x] = h[t];
}

__global__ void k_catoff(u32* __restrict__ ch, u32* __restrict__ scal) {
  if (threadIdx.x || blockIdx.x) return;
  u32 tot[8];
  for (int c = 0; c < 8; ++c) { u32 s = 0; for (int b = 0; b < NBC; ++b) s += ch[c*NBC+b]; tot[c] = s; }
  u32 run = 0;
  for (int i = 0; i < 8*NBC; ++i) { u32 v = ch[i]; ch[i] = run; run += v; }
  u32 n0 = tot[0], n1 = tot[1]+tot[2]+tot[3], n2 = tot[4]+tot[5]+tot[6], n3 = tot[7];
  u32 NF = n0 + 2u*n1 + 3u*n2 + 4u*n3;
  u32 E = scal[S_E], num = scal[S_NUM];
  u32 NEn = (u32)VN + num + 3u*NF;
  scal[S_NF] = NF; scal[S_NEN] = NEn;
  scal[S_O1] = 2u*E;
  scal[S_O2] = 2u*E + 3u*NF;
  scal[S_O3] = 2u*E + 3u*NF + 2u*NEn;
  u32 RS[8] = {0u, n0,n0,n0, n0+2u*n1, n0+2u*n1, n0+2u*n1, n0+2u*n1+3u*n2};
  u32 GS[8] = {0u, n1,n1,n1, n2,n2,n2, n3};
  u32 GP[8] = {0u, n0,n0,n0, n0+n1, n0+n1, n0+n1, n0+n1+n2};
  for (int i = 0; i < 8; ++i) { scal[S_RS+i] = RS[i]; scal[S_GS+i] = GS[i]; scal[S_GP+i] = GP[i]; }
}

__global__ void k_catrank(const u32* __restrict__ cat, const u32* __restrict__ ch,
                          u32* __restrict__ cr) {
  __shared__ u32 lds[256];
  int t = threadIdx.x;
  int base = blockIdx.x*1024 + t*4;
  u32 cc[4], loc[4];
  u32 cnt[8] = {0,0,0,0,0,0,0,0};
  for (int k = 0; k < 4; ++k) {
    int i = base + k;
    if (i < FN) { u32 c = cat[i]; cc[k] = c; loc[k] = cnt[c]++; }
    else cc[k] = 8u;
  }
  u32 tb[8];
  for (int c = 0; c < 8; ++c) {
    lds[t] = cnt[c]; __syncthreads();
    for (int o = 1; o < 256; o <<= 1) {
      u32 x = (t >= o) ? lds[t-o] : 0u; __syncthreads();
      lds[t] += x; __syncthreads();
    }
    tb[c] = lds[t] - cnt[c];
    __syncthreads();
  }
  for (int k = 0; k < 4; ++k) {
    int i = base + k;
    if (i < FN) { u32 c = cc[k]; cr[i] = ch[c*NBC + blockIdx.x] + tb[c] + loc[k]; }
  }
}

__global__ void k_wfaces(const int* __restrict__ face, const u32* __restrict__ cat,
                         const u32* __restrict__ cr, const u32* __restrict__ feid,
                         const u32* __restrict__ selr, const u32* __restrict__ scal,
                         int* __restrict__ nfi, float* __restrict__ dout) {
  int f = blockIdx.x*256 + threadIdx.x;
  if (f >= FN) return;
  const int nfc[8] = {1,2,2,2,3,3,3,4};
  const int tri[8][4][3] = {
    {{0,2,4},{0,0,0},{0,0,0},{0,0,0}},
    {{0,1,4},{1,2,4},{0,0,0},{0,0,0}},
    {{2,3,0},{3,4,0},{0,0,0},{0,0,0}},
    {{4,5,2},{5,0,2},{0,0,0},{0,0,0}},
    {{0,1,4},{1,2,3},{1,3,4},{0,0,0}},
    {{4,5,2},{5,0,1},{5,1,2},{0,0,0}},
    {{2,3,0},{3,4,5},{3,5,0},{0,0,0}},
    {{0,1,5},{1,2,3},{1,3,5},{3,4,5}}};
  u32 c = cat[f];
  int cv[6];
  cv[0] = face[f*3];   cv[2] = face[f*3+1]; cv[4] = face[f*3+2];
  cv[1] = VN + (int)selr[feid[f*3]];
  cv[3] = VN + (int)selr[feid[f*3+1]];
  cv[5] = VN + (int)selr[feid[f*3+2]];
  u32 g  = cr[f] - scal[S_GP + c];
  u32 o1 = scal[S_O1];
  for (int j = 0; j < nfc[c]; ++j) {
    u32 row = scal[S_RS + c] + (u32)j*scal[S_GS + c] + g;
    for (int m = 0; m < 3; ++m) {
      int v = cv[tri[c][j][m]];
      nfi[row*3 + m] = v;
      dout[o1 + row*3 + m] = (float)v;
    }
  }
}

__global__ void k_wne(const int* __restrict__ nfi, const u32* __restrict__ scal,
                      float* __restrict__ dout) {
  int i = blockIdx.x*256 + threadIdx.x;
  u32 NEn = scal[S_NEN];
  if (i >= (int)NEn) return;
  u32 NF = scal[S_NF];
  u32 Vp = (u32)VN + scal[S_NUM];
  u32 o2 = scal[S_O2];
  int a, b;
  if ((u32)i < Vp) { a = i; b = i; }
  else {
    u32 j = (u32)i - Vp;
    u32 blk = j / NF, r = j - blk*NF;
    int i0 = (blk == 0) ? 0 : (blk == 1) ? 1 : 2;
    int i1 = (blk == 0) ? 1 : (blk == 1) ? 2 : 0;
    a = nfi[r*3 + i0]; b = nfi[r*3 + i1];
  }
  dout[o2 + i] = (float)a;
  dout[o2 + NEn + i] = (float)b;
}

__global__ void k_wmask(const u32* __restrict__ sel, const float* __restrict__ Y,
                        const u32* __restrict__ scal, float* __restrict__ dout) {
  int e = blockIdx.x*256 + threadIdx.x;
  if (e >= (int)scal[S_E]) return;
  float y = Y[e];
  float yh = sel[e] ? 1.0f : 0.0f;
  dout[scal[S_O3] + e] = (yh - y) + y;   // straight-through value
}

// ---------------- host-side drivers ----------------
static void run_scan(u32* in, u32* out, u32* sums, int n, hipStream_t st) {
  int nb = (n + 1023) / 1024;
  scan_blocks<<<nb, 256, 0, st>>>(in, out, sums, n);
  scan_sums<<<1, 256, 0, st>>>(sums, nb);
  scan_add<<<nb, 256, 0, st>>>(out, sums, n);
}

static void radix_pass(u32* kin, u32* pin, u32* kout, u32* pout, u32* hist, u32* sums,
                       int n, int nb, int shift, bool haspay, hipStream_t st) {
  k_rhist<<<nb, 256, 0, st>>>(kin, hist, n, shift, nb);
  run_scan(hist, hist, sums, nb*256, st);
  k_rscat<<<nb, 256, 0, st>>>(kin, pin, kout, pout, hist, n, shift, nb, haspay ? 1 : 0);
}

extern "C" void kernel_launch(void* const* d_in, const int* in_sizes, int n_in,
                              void* d_out, int out_size, void* d_ws, size_t ws_size,
                              hipStream_t stream) {
  const float* x    = (const float*)d_in[0];
  const int*   face = (const int*)d_in[1];
  const int*   divp = (const int*)d_in[4];
  const float* W1s  = (const float*)d_in[5];
  const float* W1n  = (const float*)d_in[6];
  const float* b1   = (const float*)d_in[7];
  const float* W2s  = (const float*)d_in[8];
  const float* W2n  = (const float*)d_in[9];
  const float* b2   = (const float*)d_in[10];
  float* out = (float*)d_out;
  u32* W = (u32*)d_ws;

  u32 *A = W+W_A, *B = W+W_B, *PA = W+W_PA, *PB = W+W_PB;
  u32 *FL = W+W_FLAGS, *RK = W+W_RANKU, *UK = W+W_UKEYS;
  u32 *HIST = W+W_HIST, *SUMS = W+W_SUMS, *SCAL = W+W_SCAL;

  // 0) pack weights (independent of everything else)
  k_pack<<<1, 256, 0, stream>>>(W1s, W1n, b1, W2s, W2n, (float*)(W+W_PK));

  // 1) (key, origidx) sort + unique + segoff + feid
  k_keys<<<NB1, 256, 0, stream>>>(face, A, PA);
  radix_pass(A, PA, B, PB, HIST, SUMS, K3F, NB1,  0, true, stream);
  radix_pass(B, PB, A, PA, HIST, SUMS, K3F, NB1,  8, true, stream);
  radix_pass(A, PA, B, PB, HIST, SUMS, K3F, NB1, 16, true, stream);
  radix_pass(B, PB, A, PA, HIST, SUMS, K3F, NB1, 24, true, stream);
  k_uflag<<<NB1, 256, 0, stream>>>(A, FL);
  run_scan(FL, RK, SUMS, K3F, stream);
  k_uwrite<<<NB1, 256, 0, stream>>>(A, FL, RK, PA, UK, W+W_SEGOFF, W+W_FEID, SCAL, divp);

  // 2) edge nodes (+xe fused)
  k_ennode<<<NB1, 256, 0, stream>>>(UK, SCAL, x, (float*)(W+W_XE), out);

  // 3) GSN conv layers — neighbor aggregation direct from sort segments
  k_l12<<<NB1, 256, 0, stream>>>((float*)(W+W_XE), W+W_SEGOFF, PA, W+W_FEID, SCAL,
                                 (float*)(W+W_PK), (float*)(W+W_P), (float*)(W+W_Q));
  k_scores<<<NB1, 256, 0, stream>>>((float*)(W+W_P), (float*)(W+W_Q), W+W_SEGOFF, PA,
                                    W+W_FEID, b2, SCAL, (float*)(W+W_Y), W+W_YMAP);

  // 4) exact top-k (byte descent) + tie-stable selection
  k_tkinit<<<1, 256, 0, stream>>>(SCAL, HIST);
  for (int byte = 3; byte >= 0; --byte) {
    k_tkhist<<<NBH, 256, 0, stream>>>(W+W_YMAP, SCAL, HIST, byte);
    k_tksel<<<1, 1, 0, stream>>>(SCAL, HIST, byte);
  }
  k_tflag<<<NB1, 256, 0, stream>>>(W+W_YMAP, SCAL, W+W_TFLAG);
  run_scan(W+W_TFLAG, W+W_TIER, SUMS, EMAX, stream);
  k_sel<<<NB1, 256, 0, stream>>>(W+W_YMAP, W+W_TIER, SCAL, W+W_SEL);
  run_scan(W+W_SEL, W+W_SELR, SUMS, EMAX, stream);

  // 5) mesh collapse
  k_cat<<<391, 256, 0, stream>>>(W+W_FEID, W+W_SEL, W+W_CAT);
  k_cathist<<<NBC, 256, 0, stream>>>(W+W_CAT, W+W_CATH);
  k_catoff<<<1, 1, 0, stream>>>(W+W_CATH, SCAL);
  k_catrank<<<NBC, 256, 0, stream>>>(W+W_CAT, W+W_CATH, W+W_CATR);
  k_wfaces<<<391, 256, 0, stream>>>(face, W+W_CAT, W+W_CATR, W+W_FEID, W+W_SELR, SCAL,
                                    (int*)(W+W_NFI), out);
  k_wne<<<5118, 256, 0, stream>>>((int*)(W+W_NFI), SCAL, out);
  k_wmask<<<NB1, 256, 0, stream>>>(W+W_SEL, (float*)(W+W_Y), SCAL, out);
}

// Round 5
// 329.161 us; speedup vs baseline: 10.1590x; 1.1601x over previous
//
#include <hip/hip_runtime.h>
#include <stdint.h>

typedef uint32_t u32;
typedef uint64_t u64;

#define VN 50000
#define FN 100000
#define K3F 300000
#define EMAX 300000
#define NB1 1172          // ceil(300000/256)
#define NBC 98            // ceil(100000/1024)
#define NBH 293           // ceil(300000/1024)
#define NBS 293           // scan blocks for 300k/300032 elements (293*1024=300032)

// ---------------- workspace layout (u32 units) ----------------
#define W_A      0u        // 300000 keys ping
#define W_B      300000u   // 300000 keys pong
#define W_PA     600000u   // 300000 payload ping
#define W_PB     900000u   // 300000 payload pong
#define W_RANKU  1200000u  // 300000 (partial ranks)
#define W_UKEYS  1500000u  // 300000
#define W_SEGOFF 1800000u  // 300001
#define W_FEID   2100004u  // 300000
#define W_XE     2400004u  // 900000 f32
#define W_PK     3300004u  // 3072 f32 packed weights
#define W_P      3400004u  // 600000 f32
#define W_Q      4000004u  // 600000 f32
#define W_Y      4600004u  // 300000 f32
#define W_YMAP   4900004u  // 300000
#define W_T64    5200004u  // 600064 (300032 u64, 8B-aligned: offset even)
#define W_SEL    5800068u  // 300000
#define W_SELR   6100068u  // 300000
#define W_CAT    6400068u  // 100000
#define W_CATR   6500068u  // 100000
#define W_NFI    6600068u  // 1200000 int (new faces)
#define W_HIST   7800068u  // 300032
#define W_SUMS   8100100u  // 4096 (even offset -> u64-reusable)
#define W_CATH   8104196u  // 1024
#define W_SCAL   8105220u  // 64

#define S_E 0
#define S_NUM 1
#define S_PFX 2
#define S_KREM 3
#define S_TU 4
#define S_R 5
#define S_NF 6
#define S_NEN 7
#define S_O1 8
#define S_O2 9
#define S_O3 10
#define S_RS 16
#define S_GS 24
#define S_GP 32

// ---------------- threefry2x32, key = (0, 42) ----------------
__device__ __forceinline__ void tf2x32(u32 x0, u32 x1, u32& o0, u32& o1) {
  const u32 ks0 = 0u, ks1 = 42u, ks2 = 0x1BD11BDAu ^ 0u ^ 42u;
  x0 += ks0; x1 += ks1;
#define TFR(r) { x0 += x1; x1 = (x1<<(r))|(x1>>(32-(r))); x1 ^= x0; }
  TFR(13) TFR(15) TFR(26) TFR(6)   x0 += ks1; x1 += ks2 + 1u;
  TFR(17) TFR(29) TFR(16) TFR(24)  x0 += ks2; x1 += ks0 + 2u;
  TFR(13) TFR(15) TFR(26) TFR(6)   x0 += ks0; x1 += ks1 + 3u;
  TFR(17) TFR(29) TFR(16) TFR(24)  x0 += ks1; x1 += ks2 + 4u;
  TFR(13) TFR(15) TFR(26) TFR(6)   x0 += ks2; x1 += ks0 + 5u;
#undef TFR
  o0 = x0; o1 = x1;
}

// ---------------- scans (u32): block-partial + sums; consumers add sums ----------------
__global__ void scan_blocks(const u32* __restrict__ in, u32* __restrict__ out,
                            u32* __restrict__ sums, int n) {
  __shared__ u32 lds[256];
  int t = threadIdx.x;
  int base = blockIdx.x*1024 + t*4;
  u32 v[4]; u32 tot = 0;
  for (int k = 0; k < 4; ++k) { v[k] = (base+k < n) ? in[base+k] : 0u; tot += v[k]; }
  lds[t] = tot; __syncthreads();
  for (int o = 1; o < 256; o <<= 1) {
    u32 x = (t >= o) ? lds[t-o] : 0u; __syncthreads();
    lds[t] += x; __syncthreads();
  }
  u32 excl = lds[t] - tot;
  if (t == 255) sums[blockIdx.x] = lds[255];
  u32 run = excl;
  for (int k = 0; k < 4; ++k) { if (base+k < n) out[base+k] = run; run += v[k]; }
}

// scan over unique-flags computed inline from sorted keys (flag = key != prev)
__global__ void scan_flagblocks(const u32* __restrict__ sk, u32* __restrict__ out,
                                u32* __restrict__ sums, int n) {
  __shared__ u32 lds[256];
  int t = threadIdx.x;
  int base = blockIdx.x*1024 + t*4;
  u32 v[4]; u32 tot = 0;
  for (int k = 0; k < 4; ++k) {
    int i = base + k;
    u32 f = 0;
    if (i < n) f = (i == 0 || sk[i-1] != sk[i]) ? 1u : 0u;
    v[k] = f; tot += f;
  }
  lds[t] = tot; __syncthreads();
  for (int o = 1; o < 256; o <<= 1) {
    u32 x = (t >= o) ? lds[t-o] : 0u; __syncthreads();
    lds[t] += x; __syncthreads();
  }
  u32 excl = lds[t] - tot;
  if (t == 255) sums[blockIdx.x] = lds[255];
  u32 run = excl;
  for (int k = 0; k < 4; ++k) { if (base+k < n) out[base+k] = run; run += v[k]; }
}

__global__ void scan_sums(u32* __restrict__ s, int nb) {
  __shared__ u32 lds[256];
  __shared__ u32 carry;
  int t = threadIdx.x;
  if (t == 0) carry = 0;
  __syncthreads();
  for (int base = 0; base < nb; base += 1024) {
    int idx = base + t*4;
    u32 v[4]; u32 tot = 0;
    for (int k = 0; k < 4; ++k) { v[k] = (idx+k < nb) ? s[idx+k] : 0u; tot += v[k]; }
    lds[t] = tot; __syncthreads();
    for (int o = 1; o < 256; o <<= 1) {
      u32 x = (t >= o) ? lds[t-o] : 0u; __syncthreads();
      lds[t] += x; __syncthreads();
    }
    u32 excl = lds[t] - tot;
    u32 ctot = lds[255];
    u32 c = carry;
    __syncthreads();
    u32 run = c + excl;
    for (int k = 0; k < 4; ++k) { if (idx+k < nb) s[idx+k] = run; run += v[k]; }
    if (t == 0) carry = c + ctot;
    __syncthreads();
  }
}

// ---------------- u64 packed scan (gt in lo32, tie in hi32) ----------------
__global__ void scan64_src(const u32* __restrict__ ymap, const u32* __restrict__ scal,
                           u64* __restrict__ part, u64* __restrict__ sums) {
  __shared__ u64 lds[256];
  int t = threadIdx.x;
  int base = blockIdx.x*1024 + t*4;
  int E = (int)scal[S_E];
  u32 TU = scal[S_TU];
  u64 v[4]; u64 tot = 0;
  for (int k = 0; k < 4; ++k) {
    int e = base + k;
    u64 val = 0;
    if (e < E) {
      u32 u = ymap[e];
      if (u > TU) val = 1ull;
      else if (u == TU) val = 1ull << 32;
    }
    v[k] = val; tot += val;
  }
  lds[t] = tot; __syncthreads();
  for (int o = 1; o < 256; o <<= 1) {
    u64 x = (t >= o) ? lds[t-o] : 0ull; __syncthreads();
    lds[t] += x; __syncthreads();
  }
  u64 excl = lds[t] - tot;
  if (t == 255) sums[blockIdx.x] = lds[255];
  u64 run = excl;
  for (int k = 0; k < 4; ++k) { part[base+k] = run; run += v[k]; }
}

__global__ void scan64_sums(u64* __restrict__ s, int nb) {
  __shared__ u64 lds[256];
  int t = threadIdx.x;
  int idx = t*4;
  u64 v[4]; u64 tot = 0;
  for (int k = 0; k < 4; ++k) { v[k] = (idx+k < nb) ? s[idx+k] : 0ull; tot += v[k]; }
  lds[t] = tot; __syncthreads();
  for (int o = 1; o < 256; o <<= 1) {
    u64 x = (t >= o) ? lds[t-o] : 0ull; __syncthreads();
    lds[t] += x; __syncthreads();
  }
  u64 excl = lds[t] - tot;
  u64 run = excl;
  for (int k = 0; k < 4; ++k) { if (idx+k < nb) s[idx+k] = run; run += v[k]; }
}

// sel + selr directly from packed prefix: selected = gt || (tie && TIEpre < R);
// rank among selected = GTpre + min(TIEpre, R)  (== old tier/selr scans)
__global__ void k_sel2(const u32* __restrict__ ymap, const u64* __restrict__ part,
                       const u64* __restrict__ sums, const u32* __restrict__ scal,
                       u32* __restrict__ sel, u32* __restrict__ selr) {
  int e = blockIdx.x*256 + threadIdx.x;
  if (e >= EMAX) return;
  int E = (int)scal[S_E];
  u32 TU = scal[S_TU], R = scal[S_R];
  u64 pre = part[e] + sums[e>>10];
  u32 GTpre = (u32)pre, TIEpre = (u32)(pre >> 32);
  u32 v = 0;
  if (e < E) {
    u32 u = ymap[e];
    v = (u > TU) || (u == TU && TIEpre < R);
  }
  sel[e] = v ? 1u : 0u;
  selr[e] = GTpre + min(TIEpre, R);
}

// ---------------- radix sort (8-bit LSD, stable) ----------------
__global__ void k_rhist(const u32* __restrict__ keys, u32* __restrict__ hist,
                        int n, int shift, int nb) {
  __shared__ u32 h[256];
  int t = threadIdx.x;
  h[t] = 0; __syncthreads();
  int i = blockIdx.x*256 + t;
  if (i < n) atomicAdd(&h[(keys[i]>>shift)&255u], 1u);
  __syncthreads();
  hist[(u32)t*nb + blockIdx.x] = h[t];
}

__global__ void k_rscat(const u32* __restrict__ keys, const u32* __restrict__ pay,
                        u32* __restrict__ okeys, u32* __restrict__ opay,
                        const u32* __restrict__ hist, const u32* __restrict__ sums,
                        int n, int shift, int nb) {
  __shared__ u64 ball[4][8];
  __shared__ u64 vmask[4];
  int t = threadIdx.x, w = t>>6, lane = t&63;
  int i = blockIdx.x*256 + t;
  bool valid = i < n;
  u32 k = valid ? keys[i] : 0u;
  u32 d = (k>>shift)&255u;
  for (int bit = 0; bit < 8; ++bit) {
    u64 bm = __ballot(valid && ((d>>bit)&1u));
    if (lane == 0) ball[w][bit] = bm;
  }
  u64 vb = __ballot(valid ? 1 : 0);
  if (lane == 0) vmask[w] = vb;
  __syncthreads();
  if (valid) {
    u32 rank = 0;
    for (int ww = 0; ww < w; ++ww) {
      u64 m = vmask[ww];
      for (int bit = 0; bit < 8; ++bit) { u64 bb = ball[ww][bit]; m &= ((d>>bit)&1u) ? bb : ~bb; }
      rank += (u32)__popcll(m);
    }
    u64 m = vmask[w];
    for (int bit = 0; bit < 8; ++bit) { u64 bb = ball[w][bit]; m &= ((d>>bit)&1u) ? bb : ~bb; }
    rank += (u32)__popcll(m & ((1ull<<lane)-1ull));
    u32 h = d*(u32)nb + blockIdx.x;
    u32 pos = hist[h] + sums[h>>10] + rank;
    okeys[pos] = k;
    opay[pos] = pay[i];
  }
}

// ---------------- pipeline kernels ----------------
__global__ void k_keys(const int* __restrict__ face, u32* __restrict__ keys,
                       u32* __restrict__ pay) {
  int i = blockIdx.x*256 + threadIdx.x;
  if (i >= K3F) return;
  int s = i / FN, f = i - s*FN;
  int v0 = face[f*3 + s];
  int v1 = face[f*3 + (s == 2 ? 0 : s+1)];
  int a = min(v0, v1), b = max(v0, v1);
  u32 key = (u32)a * (u32)VN + (u32)b;   // int32 wraparound, matches jnp
  keys[i] = key ^ 0x80000000u;           // biased: unsigned order == signed order
  pay[i] = (u32)i;                       // original index = s*FN + f
}

// unique keys + segment offsets + feid scatter; rank = partial + sums (scan_add folded in)
__global__ void k_uwrite(const u32* __restrict__ sk, const u32* __restrict__ rankp,
                         const u32* __restrict__ sums, const u32* __restrict__ pay,
                         u32* __restrict__ ukeys, u32* __restrict__ segoff,
                         u32* __restrict__ feid,
                         u32* __restrict__ scal, const int* __restrict__ divp) {
  int p = blockIdx.x*256 + threadIdx.x;
  if (p >= K3F) return;
  u32 cur = sk[p];
  u32 fl = (p == 0 || sk[p-1] != cur) ? 1u : 0u;
  u32 rk = rankp[p] + sums[p>>10];
  if (fl) { ukeys[rk] = cur; segoff[rk] = (u32)p; }
  u32 id = rk - 1u + fl;
  u32 i = pay[p];
  u32 s = i / FN, f = i - s*FN;
  feid[f*3 + s] = id;
  if (p == K3F-1) {
    u32 E = rk + fl;
    scal[S_E] = E; scal[S_NUM] = E / (u32)divp[0];
    segoff[E] = (u32)K3F;
  }
}

// edge endpoints (output 0) + xe gather, fused
__global__ void k_ennode(const u32* __restrict__ ukeys, const u32* __restrict__ scal,
                         const float* __restrict__ x,
                         float* __restrict__ xe, float* __restrict__ dout) {
  int e = blockIdx.x*256 + threadIdx.x;
  if (e >= (int)scal[S_E]) return;
  int k = (int)(ukeys[e] ^ 0x80000000u);
  long long kk = (long long)k;
  long long qq = (kk - (kk < 0 ? (long long)(VN-1) : 0ll)) / VN; // floor div
  int q = (int)qq;
  int r = (int)(kk - qq * VN);
  dout[2*e]   = (float)q;
  dout[2*e+1] = (float)r;
  u32 i0 = (u32)(q < 0 ? q + VN : q);  // numpy-style negative index wrap
  u32 i1 = (u32)r;
  for (int c = 0; c < 3; ++c) xe[e*3+c] = 0.5f*(x[i0*3+c] + x[i1*3+c]);
}

// pack weights per hidden unit: [h][0..11] = W1s[0..2], W1n[0..2], b1, W2s[0..1], W2n[0..1], pad
__global__ void k_pack(const float* __restrict__ W1s, const float* __restrict__ W1n,
                       const float* __restrict__ b1,
                       const float* __restrict__ W2s, const float* __restrict__ W2n,
                       float* __restrict__ pk) {
  int h = threadIdx.x;
  if (h >= 256) return;
  float* p = pk + h*12;
  p[0] = W1s[h]; p[1] = W1s[256+h]; p[2] = W1s[512+h];
  p[3] = W1n[h]; p[4] = W1n[256+h]; p[5] = W1n[512+h];
  p[6] = b1[h];
  p[7] = W2s[2*h]; p[8] = W2s[2*h+1];
  p[9] = W2n[2*h]; p[10] = W2n[2*h+1];
  p[11] = 0.0f;
}

// Neighbor aggregation direct from key-sort segments (bit-exact reference order).
__device__ __forceinline__ void agg_neighbors(int e, u32 st, u32 en,
                                              const u32* __restrict__ pay,
                                              const u32* __restrict__ feid,
                                              const float* __restrict__ v, int stride,
                                              float* acc0, float* acc1, float* acc2) {
  const int sslot[6] = {0,1,1,2,2,0};
  const int dslot[6] = {1,0,2,1,0,2};
  float c0 = 0.f, c1 = 0.f, c2 = 0.f;
  for (int b = 0; b < 6; ++b) {
    int j = dslot[b], isl = sslot[b];
    for (u32 p = st; p < en; ++p) {
      u32 i = pay[p];
      u32 s = i / FN;
      if ((int)s == j) {
        u32 f = i - s*FN;
        u32 u = feid[f*3 + isl];
        c0 += v[u*stride]; c1 += v[u*stride+1]; if (stride == 3) c2 += v[u*stride+2];
      }
    }
  }
  c0 += v[e*stride]; c1 += v[e*stride+1]; if (stride == 3) c2 += v[e*stride+2];
  *acc0 = c0; *acc1 = c1; *acc2 = c2;
}

// fused neighbor-mean + layer1(relu-gsnconv) + projection, thread-per-edge.
__global__ void k_l12(const float* __restrict__ xe, const u32* __restrict__ segoff,
                      const u32* __restrict__ pay, const u32* __restrict__ feid,
                      const u32* __restrict__ scal, const float* __restrict__ pk,
                      float* __restrict__ P, float* __restrict__ Q) {
  int e = blockIdx.x*256 + threadIdx.x;
  if (e >= (int)scal[S_E]) return;
  u32 st = segoff[e], en = segoff[e+1];
  float c0, c1, c2;
  agg_neighbors(e, st, en, pay, feid, xe, 3, &c0, &c1, &c2);
  float x0 = xe[e*3], x1 = xe[e*3+1], x2 = xe[e*3+2];
  float dg = (float)(2u*(en - st) + 1u);
  float m0 = c0/dg, m1 = c1/dg, m2 = c2/dg;
  float p0 = 0.f, p1 = 0.f, q0 = 0.f, q1 = 0.f;
#pragma unroll 8
  for (int hh = 0; hh < 256; ++hh) {
    const float* w = pk + hh*12;
    float s1 = x0*w[0] + x1*w[1] + x2*w[2];
    float s2 = m0*w[3] + m1*w[4] + m2*w[5];
    float h = fmaxf(s1 + s2 + w[6], 0.0f);
    p0 += h*w[7];  p1 += h*w[8];
    q0 += h*w[9];  q1 += h*w[10];
  }
  P[2*e] = p0; P[2*e+1] = p1; Q[2*e] = q0; Q[2*e+1] = q1;
}

__global__ void k_scores(const float* __restrict__ P, const float* __restrict__ Q,
                         const u32* __restrict__ segoff, const u32* __restrict__ pay,
                         const u32* __restrict__ feid,
                         const float* __restrict__ b2, const u32* __restrict__ scal,
                         float* __restrict__ Y, u32* __restrict__ ymap) {
  int e = blockIdx.x*256 + threadIdx.x;
  u32 E = scal[S_E];
  if (e >= (int)E) return;
  u32 st = segoff[e], en = segoff[e+1];
  float a0, a1, dummy;
  agg_neighbors(e, st, en, pay, feid, Q, 2, &a0, &a1, &dummy);
  float dg = (float)(2u*(en - st) + 1u);
  float z0 = P[2*e]   + a0/dg + b2[0];
  float z1 = P[2*e+1] + a1/dg + b2[1];
  float l0 = 1.0f/(1.0f + expf(-z0));
  float l1 = 1.0f/(1.0f + expf(-z1));
  // JAX partitionable threefry: bits(i) = o0^o1 of threefry(key=(0,42), counts)
  u32 g0b, g1b;
  { u32 o0,o1; tf2x32(0u, 2u*(u32)e,      o0, o1); g0b = o0 ^ o1; }
  { u32 o0,o1; tf2x32(0u, 2u*(u32)e + 1u, o0, o1); g1b = o0 ^ o1; }
  float U0 = __uint_as_float((g0b>>9) | 0x3f800000u) - 1.0f;
  float U1 = __uint_as_float((g1b>>9) | 0x3f800000u) - 1.0f;
  float g0 = -logf(-logf(U0 + 1e-20f) + 1e-20f);
  float g1 = -logf(-logf(U1 + 1e-20f) + 1e-20f);
  float A0 = (l0 + g0)/0.1f;
  float A1 = (l1 + g1)/0.1f;
  float mx = fmaxf(A0, A1);
  float e0 = expf(A0-mx), e1 = expf(A1-mx);
  float y = e0/(e0+e1);
  Y[e] = y;
  ymap[e] = __float_as_uint(y) | 0x80000000u;   // monotone map (y >= 0)
}

// ---------------- exact top-k threshold (byte-wise descent) ----------------
__global__ void k_tkinit(u32* __restrict__ scal, u32* __restrict__ hist) {
  int t = threadIdx.x;
  if (t < 256) hist[t] = 0u;
  if (t == 0) { scal[S_PFX] = 0u; scal[S_KREM] = scal[S_NUM]; }
}

// two-level histogram: LDS per block, then one global atomic per non-zero bucket.
__global__ void k_tkhist(const u32* __restrict__ ymap, const u32* __restrict__ scal,
                         u32* __restrict__ hist, int byte) {
  __shared__ u32 h[256];
  int t = threadIdx.x;
  h[t] = 0u; __syncthreads();
  int E = (int)scal[S_E];
  u32 pfx = scal[S_PFX];
  int base = blockIdx.x*1024;
  for (int k = 0; k < 4; ++k) {
    int e = base + k*256 + t;
    if (e < E) {
      u32 u = ymap[e];
      bool match = (byte == 3) || ((u >> ((byte+1)*8)) == pfx);
      if (match) atomicAdd(&h[(u >> (byte*8)) & 255u], 1u);
    }
  }
  __syncthreads();
  u32 c = h[t];
  if (c) atomicAdd(&hist[t], c);
}

// parallel bucket select: suffix sums in LDS, chosen = max b with suffix(b) >= krem
// (identical to the serial descending-subtract loop); hist zeroed for next pass.
__global__ void k_tksel(u32* __restrict__ scal, u32* __restrict__ hist, int byte) {
  __shared__ u32 s2[256];
  __shared__ u32 chosen_s;
  int t = threadIdx.x;
  u32 v = hist[t];
  hist[t] = 0u;
  s2[t] = v;
  if (t == 0) chosen_s = 0u;
  __syncthreads();
  for (int o = 1; o < 256; o <<= 1) {
    u32 x = (t + o < 256) ? s2[t+o] : 0u; __syncthreads();
    s2[t] += x; __syncthreads();
  }
  u32 krem = scal[S_KREM];
  if (s2[t] >= krem) atomicMax(&chosen_s, (u32)t);
  __syncthreads();
  if (t == 0) {
    u32 chosen = chosen_s;
    u32 sufnext = (chosen < 255u) ? s2[chosen+1] : 0u;
    u32 newkrem = krem - sufnext;
    u32 pfx = (scal[S_PFX] << 8) | chosen;
    scal[S_PFX] = pfx; scal[S_KREM] = newkrem;
    if (byte == 0) { scal[S_TU] = pfx; scal[S_R] = newkrem; }
  }
}

// ---------------- mesh collapse ----------------
__global__ void k_cat(const u32* __restrict__ feid, const u32* __restrict__ sel,
                      u32* __restrict__ cat) {
  int f = blockIdx.x*256 + threadIdx.x;
  if (f >= FN) return;
  u32 m0 = sel[feid[f*3]], m1 = sel[feid[f*3+1]], m2 = sel[feid[f*3+2]];
  u32 pen = m0 + m1 + m2;
  u32 psi = m1 + 2u*m2;
  u32 c = (pen == 0) ? 0u : (pen == 1) ? (1u+psi) : (pen == 2) ? (3u+psi) : 7u;
  cat[f] = c;
}

__global__ void k_cathist(const u32* __restrict__ cat, u32* __restrict__ ch) {
  __shared__ u32 h[8];
  int t = threadIdx.x;
  if (t < 8) h[t] = 0u;
  __syncthreads();
  int base = blockIdx.x*1024 + t*4;
  for (int k = 0; k < 4; ++k) if (base+k < FN) atomicAdd(&h[cat[base+k]], 1u);
  __syncthreads();
  if (t < 8) ch[(u32)t*NBC + blockIdx.x] = h[t];
}

// parallel category-offset computation: LDS scan of 784 entries + scalar tail
// (was <<<1,1>>> with 784 serial global loads -> 57 us)
__global__ void k_catoff(u32* __restrict__ ch, u32* __restrict__ scal) {
  __shared__ u32 lds[256];
  __shared__ u32 ex[1024];
  int t = threadIdx.x;
  u32 v[4]; u32 tot = 0;
  for (int k = 0; k < 4; ++k) {
    int i = t*4 + k;
    u32 x = (i < 8*NBC) ? ch[i] : 0u;
    v[k] = x; tot += x;
  }
  lds[t] = tot; __syncthreads();
  for (int o = 1; o < 256; o <<= 1) {
    u32 x = (t >= o) ? lds[t-o] : 0u; __syncthreads();
    lds[t] += x; __syncthreads();
  }
  u32 excl = lds[t] - tot;
  u32 run = excl;
  for (int k = 0; k < 4; ++k) { ex[t*4+k] = run; run += v[k]; }
  __syncthreads();
  for (int k = 0; k < 4; ++k) {
    int i = t*4 + k;
    if (i < 8*NBC) ch[i] = ex[i];
  }
  if (t == 0) {
    u32 total = lds[255];
    u32 bnd[9];
    for (int c = 0; c < 8; ++c) bnd[c] = ex[c*NBC];
    bnd[8] = total;
    u32 tot8[8];
    for (int c = 0; c < 8; ++c) tot8[c] = bnd[c+1] - bnd[c];
    u32 n0 = tot8[0], n1 = tot8[1]+tot8[2]+tot8[3], n2 = tot8[4]+tot8[5]+tot8[6], n3 = tot8[7];
    u32 NF = n0 + 2u*n1 + 3u*n2 + 4u*n3;
    u32 E = scal[S_E], num = scal[S_NUM];
    u32 NEn = (u32)VN + num + 3u*NF;
    scal[S_NF] = NF; scal[S_NEN] = NEn;
    scal[S_O1] = 2u*E;
    scal[S_O2] = 2u*E + 3u*NF;
    scal[S_O3] = 2u*E + 3u*NF + 2u*NEn;
    u32 RS[8] = {0u, n0,n0,n0, n0+2u*n1, n0+2u*n1, n0+2u*n1, n0+2u*n1+3u*n2};
    u32 GS[8] = {0u, n1,n1,n1, n2,n2,n2, n3};
    u32 GP[8] = {0u, n0,n0,n0, n0+n1, n0+n1, n0+n1, n0+n1+n2};
    for (int i = 0; i < 8; ++i) { scal[S_RS+i] = RS[i]; scal[S_GS+i] = GS[i]; scal[S_GP+i] = GP[i]; }
  }
}

__global__ void k_catrank(const u32* __restrict__ cat, const u32* __restrict__ ch,
                          u32* __restrict__ cr) {
  __shared__ u32 lds[256];
  int t = threadIdx.x;
  int base = blockIdx.x*1024 + t*4;
  u32 cc[4], loc[4];
  u32 cnt[8] = {0,0,0,0,0,0,0,0};
  for (int k = 0; k < 4; ++k) {
    int i = base + k;
    if (i < FN) { u32 c = cat[i]; cc[k] = c; loc[k] = cnt[c]++; }
    else cc[k] = 8u;
  }
  u32 tb[8];
  for (int c = 0; c < 8; ++c) {
    lds[t] = cnt[c]; __syncthreads();
    for (int o = 1; o < 256; o <<= 1) {
      u32 x = (t >= o) ? lds[t-o] : 0u; __syncthreads();
      lds[t] += x; __syncthreads();
    }
    tb[c] = lds[t] - cnt[c];
    __syncthreads();
  }
  for (int k = 0; k < 4; ++k) {
    int i = base + k;
    if (i < FN) { u32 c = cc[k]; cr[i] = ch[c*NBC + blockIdx.x] + tb[c] + loc[k]; }
  }
}

__global__ void k_wfaces(const int* __restrict__ face, const u32* __restrict__ cat,
                         const u32* __restrict__ cr, const u32* __restrict__ feid,
                         const u32* __restrict__ selr, const u32* __restrict__ scal,
                         int* __restrict__ nfi, float* __restrict__ dout) {
  int f = blockIdx.x*256 + threadIdx.x;
  if (f >= FN) return;
  const int nfc[8] = {1,2,2,2,3,3,3,4};
  const int tri[8][4][3] = {
    {{0,2,4},{0,0,0},{0,0,0},{0,0,0}},
    {{0,1,4},{1,2,4},{0,0,0},{0,0,0}},
    {{2,3,0},{3,4,0},{0,0,0},{0,0,0}},
    {{4,5,2},{5,0,2},{0,0,0},{0,0,0}},
    {{0,1,4},{1,2,3},{1,3,4},{0,0,0}},
    {{4,5,2},{5,0,1},{5,1,2},{0,0,0}},
    {{2,3,0},{3,4,5},{3,5,0},{0,0,0}},
    {{0,1,5},{1,2,3},{1,3,5},{3,4,5}}};
  u32 c = cat[f];
  int cv[6];
  cv[0] = face[f*3];   cv[2] = face[f*3+1]; cv[4] = face[f*3+2];
  cv[1] = VN + (int)selr[feid[f*3]];
  cv[3] = VN + (int)selr[feid[f*3+1]];
  cv[5] = VN + (int)selr[feid[f*3+2]];
  u32 g  = cr[f] - scal[S_GP + c];
  u32 o1 = scal[S_O1];
  for (int j = 0; j < nfc[c]; ++j) {
    u32 row = scal[S_RS + c] + (u32)j*scal[S_GS + c] + g;
    for (int m = 0; m < 3; ++m) {
      int v = cv[tri[c][j][m]];
      nfi[row*3 + m] = v;
      dout[o1 + row*3 + m] = (float)v;
    }
  }
}

__global__ void k_wne(const int* __restrict__ nfi, const u32* __restrict__ scal,
                      float* __restrict__ dout) {
  int i = blockIdx.x*256 + threadIdx.x;
  u32 NEn = scal[S_NEN];
  if (i >= (int)NEn) return;
  u32 NF = scal[S_NF];
  u32 Vp = (u32)VN + scal[S_NUM];
  u32 o2 = scal[S_O2];
  int a, b;
  if ((u32)i < Vp) { a = i; b = i; }
  else {
    u32 j = (u32)i - Vp;
    u32 blk = j / NF, r = j - blk*NF;
    int i0 = (blk == 0) ? 0 : (blk == 1) ? 1 : 2;
    int i1 = (blk == 0) ? 1 : (blk == 1) ? 2 : 0;
    a = nfi[r*3 + i0]; b = nfi[r*3 + i1];
  }
  dout[o2 + i] = (float)a;
  dout[o2 + NEn + i] = (float)b;
}

__global__ void k_wmask(const u32* __restrict__ sel, const float* __restrict__ Y,
                        const u32* __restrict__ scal, float* __restrict__ dout) {
  int e = blockIdx.x*256 + threadIdx.x;
  if (e >= (int)scal[S_E]) return;
  float y = Y[e];
  float yh = sel[e] ? 1.0f : 0.0f;
  dout[scal[S_O3] + e] = (yh - y) + y;   // straight-through value
}

// ---------------- host-side drivers ----------------
static void radix_pass(u32* kin, u32* pin, u32* kout, u32* pout, u32* hist, u32* sums,
                       int n, int nb, int shift, hipStream_t st) {
  k_rhist<<<nb, 256, 0, st>>>(kin, hist, n, shift, nb);
  int nscan = nb*256;
  int nbs = (nscan + 1023)/1024;
  scan_blocks<<<nbs, 256, 0, st>>>(hist, hist, sums, nscan);
  scan_sums<<<1, 256, 0, st>>>(sums, nbs);
  k_rscat<<<nb, 256, 0, st>>>(kin, pin, kout, pout, hist, sums, n, shift, nb);
}

extern "C" void kernel_launch(void* const* d_in, const int* in_sizes, int n_in,
                              void* d_out, int out_size, void* d_ws, size_t ws_size,
                              hipStream_t stream) {
  const float* x    = (const float*)d_in[0];
  const int*   face = (const int*)d_in[1];
  const int*   divp = (const int*)d_in[4];
  const float* W1s  = (const float*)d_in[5];
  const float* W1n  = (const float*)d_in[6];
  const float* b1   = (const float*)d_in[7];
  const float* W2s  = (const float*)d_in[8];
  const float* W2n  = (const float*)d_in[9];
  const float* b2   = (const float*)d_in[10];
  float* out = (float*)d_out;
  u32* W = (u32*)d_ws;

  u32 *A = W+W_A, *B = W+W_B, *PA = W+W_PA, *PB = W+W_PB;
  u32 *RK = W+W_RANKU, *UK = W+W_UKEYS;
  u32 *HIST = W+W_HIST, *SUMS = W+W_SUMS, *SCAL = W+W_SCAL;
  u64 *T64 = (u64*)(W+W_T64);
  u64 *SUMS64 = (u64*)(W+W_SUMS);

  // 0) pack weights (independent of everything else)
  k_pack<<<1, 256, 0, stream>>>(W1s, W1n, b1, W2s, W2n, (float*)(W+W_PK));

  // 1) (key, origidx) sort + unique + segoff + feid
  k_keys<<<NB1, 256, 0, stream>>>(face, A, PA);
  radix_pass(A, PA, B, PB, HIST, SUMS, K3F, NB1,  0, stream);
  radix_pass(B, PB, A, PA, HIST, SUMS, K3F, NB1,  8, stream);
  radix_pass(A, PA, B, PB, HIST, SUMS, K3F, NB1, 16, stream);
  radix_pass(B, PB, A, PA, HIST, SUMS, K3F, NB1, 24, stream);
  scan_flagblocks<<<NBS, 256, 0, stream>>>(A, RK, SUMS, K3F);
  scan_sums<<<1, 256, 0, stream>>>(SUMS, NBS);
  k_uwrite<<<NB1, 256, 0, stream>>>(A, RK, SUMS, PA, UK, W+W_SEGOFF, W+W_FEID, SCAL, divp);

  // 2) edge nodes (+xe fused)
  k_ennode<<<NB1, 256, 0, stream>>>(UK, SCAL, x, (float*)(W+W_XE), out);

  // 3) GSN conv layers — neighbor aggregation direct from sort segments
  k_l12<<<NB1, 256, 0, stream>>>((float*)(W+W_XE), W+W_SEGOFF, PA, W+W_FEID, SCAL,
                                 (float*)(W+W_PK), (float*)(W+W_P), (float*)(W+W_Q));
  k_scores<<<NB1, 256, 0, stream>>>((float*)(W+W_P), (float*)(W+W_Q), W+W_SEGOFF, PA,
                                    W+W_FEID, b2, SCAL, (float*)(W+W_Y), W+W_YMAP);

  // 4) exact top-k (byte descent) + packed u64 scan for sel/selr
  k_tkinit<<<1, 256, 0, stream>>>(SCAL, HIST);
  for (int byte = 3; byte >= 0; --byte) {
    k_tkhist<<<NBH, 256, 0, stream>>>(W+W_YMAP, SCAL, HIST, byte);
    k_tksel<<<1, 256, 0, stream>>>(SCAL, HIST, byte);
  }
  scan64_src<<<NBS, 256, 0, stream>>>(W+W_YMAP, SCAL, T64, SUMS64);
  scan64_sums<<<1, 256, 0, stream>>>(SUMS64, NBS);
  k_sel2<<<NB1, 256, 0, stream>>>(W+W_YMAP, T64, SUMS64, SCAL, W+W_SEL, W+W_SELR);

  // 5) mesh collapse
  k_cat<<<391, 256, 0, stream>>>(W+W_FEID, W+W_SEL, W+W_CAT);
  k_cathist<<<NBC, 256, 0, stream>>>(W+W_CAT, W+W_CATH);
  k_catoff<<<1, 256, 0, stream>>>(W+W_CATH, SCAL);
  k_catrank<<<NBC, 256, 0, stream>>>(W+W_CAT, W+W_CATH, W+W_CATR);
  k_wfaces<<<391, 256, 0, stream>>>(face, W+W_CAT, W+W_CATR, W+W_FEID, W+W_SELR, SCAL,
                                    (int*)(W+W_NFI), out);
  k_wne<<<5118, 256, 0, stream>>>((int*)(W+W_NFI), SCAL, out);
  k_wmask<<<NB1, 256, 0, stream>>>(W+W_SEL, (float*)(W+W_Y), SCAL, out);
}

// Round 6
// 319.989 us; speedup vs baseline: 10.4502x; 1.0287x over previous
//
#include <hip/hip_runtime.h>
#include <stdint.h>

typedef uint32_t u32;
typedef uint64_t u64;

#define VN 50000
#define FN 100000
#define K3F 300000
#define EMAX 300000
#define NB1 1172          // ceil(300000/256)
#define NBC 98            // ceil(100000/1024)
#define NBH 293           // ceil(300000/1024)
#define NBS 293           // scan blocks (293*1024=300032)

// ---------------- workspace layout (u32 units) ----------------
#define W_KPA    0u        // 600000 (300000 u64 key|pay) ping
#define W_KPB    600000u   // 600000 pong
#define W_RANKU  1200000u  // 300000 (partial flag ranks)
#define W_SEGOFF 1500000u  // 300001
#define W_FEID   1800004u  // 300000
#define W_XE     2100004u  // 900000 f32
#define W_PK     3000004u  // 3072 f32 packed weights
#define W_P      3100004u  // 600000 f32
#define W_Q      3700004u  // 600000 f32
#define W_Y      4300004u  // 300000 f32
#define W_YMAP   4600004u  // 300000
#define W_T64    4900004u  // 600064 (300032 u64; offset even -> 8B aligned)
#define W_SEL    5500068u  // 300000
#define W_SELR   5800068u  // 300000
#define W_CAT    6100068u  // 100000
#define W_CATR   6200068u  // 100000
#define W_NFI    6300068u  // 1200000 int (new faces)
#define W_HIST   7500068u  // 300032 radix hist
#define W_SUMS   7800100u  // 4096 (even -> u64-reusable)
#define W_CATH   7804196u  // 1024
#define W_TKH    7805220u  // 256 top-k hist
#define W_DONE   7805476u  // 16 done counters
#define W_SCAL   7805504u  // 64

#define S_E 0
#define S_NUM 1
#define S_PFX 2
#define S_KREM 3
#define S_TU 4
#define S_R 5
#define S_NF 6
#define S_NEN 7
#define S_O1 8
#define S_O2 9
#define S_O3 10
#define S_RS 16
#define S_GS 24
#define S_GP 32

// ---------------- threefry2x32, key = (0, 42) ----------------
__device__ __forceinline__ void tf2x32(u32 x0, u32 x1, u32& o0, u32& o1) {
  const u32 ks0 = 0u, ks1 = 42u, ks2 = 0x1BD11BDAu ^ 0u ^ 42u;
  x0 += ks0; x1 += ks1;
#define TFR(r) { x0 += x1; x1 = (x1<<(r))|(x1>>(32-(r))); x1 ^= x0; }
  TFR(13) TFR(15) TFR(26) TFR(6)   x0 += ks1; x1 += ks2 + 1u;
  TFR(17) TFR(29) TFR(16) TFR(24)  x0 += ks2; x1 += ks0 + 2u;
  TFR(13) TFR(15) TFR(26) TFR(6)   x0 += ks0; x1 += ks1 + 3u;
  TFR(17) TFR(29) TFR(16) TFR(24)  x0 += ks1; x1 += ks2 + 4u;
  TFR(13) TFR(15) TFR(26) TFR(6)   x0 += ks2; x1 += ks0 + 5u;
#undef TFR
  o0 = x0; o1 = x1;
}

// ---------------- scans (u32): block-partial + sums; consumers add sums ----------------
__global__ void scan_blocks(const u32* __restrict__ in, u32* __restrict__ out,
                            u32* __restrict__ sums, int n) {
  __shared__ u32 lds[256];
  int t = threadIdx.x;
  int base = blockIdx.x*1024 + t*4;
  u32 v[4]; u32 tot = 0;
  for (int k = 0; k < 4; ++k) { v[k] = (base+k < n) ? in[base+k] : 0u; tot += v[k]; }
  lds[t] = tot; __syncthreads();
  for (int o = 1; o < 256; o <<= 1) {
    u32 x = (t >= o) ? lds[t-o] : 0u; __syncthreads();
    lds[t] += x; __syncthreads();
  }
  u32 excl = lds[t] - tot;
  if (t == 255) sums[blockIdx.x] = lds[255];
  u32 run = excl;
  for (int k = 0; k < 4; ++k) { if (base+k < n) out[base+k] = run; run += v[k]; }
}

// scan over unique-flags computed inline from sorted packed keys (flag = hikey != prev)
__global__ void scan_flagblocks(const u64* __restrict__ kp, u32* __restrict__ out,
                                u32* __restrict__ sums, int n) {
  __shared__ u32 lds[256];
  int t = threadIdx.x;
  int base = blockIdx.x*1024 + t*4;
  u32 v[4]; u32 tot = 0;
  for (int k = 0; k < 4; ++k) {
    int i = base + k;
    u32 f = 0;
    if (i < n) f = (i == 0 || (u32)(kp[i-1]>>32) != (u32)(kp[i]>>32)) ? 1u : 0u;
    v[k] = f; tot += f;
  }
  lds[t] = tot; __syncthreads();
  for (int o = 1; o < 256; o <<= 1) {
    u32 x = (t >= o) ? lds[t-o] : 0u; __syncthreads();
    lds[t] += x; __syncthreads();
  }
  u32 excl = lds[t] - tot;
  if (t == 255) sums[blockIdx.x] = lds[255];
  u32 run = excl;
  for (int k = 0; k < 4; ++k) { if (base+k < n) out[base+k] = run; run += v[k]; }
}

__global__ void scan_sums(u32* __restrict__ s, int nb) {
  __shared__ u32 lds[256];
  __shared__ u32 carry;
  int t = threadIdx.x;
  if (t == 0) carry = 0;
  __syncthreads();
  for (int base = 0; base < nb; base += 1024) {
    int idx = base + t*4;
    u32 v[4]; u32 tot = 0;
    for (int k = 0; k < 4; ++k) { v[k] = (idx+k < nb) ? s[idx+k] : 0u; tot += v[k]; }
    lds[t] = tot; __syncthreads();
    for (int o = 1; o < 256; o <<= 1) {
      u32 x = (t >= o) ? lds[t-o] : 0u; __syncthreads();
      lds[t] += x; __syncthreads();
    }
    u32 excl = lds[t] - tot;
    u32 ctot = lds[255];
    u32 c = carry;
    __syncthreads();
    u32 run = c + excl;
    for (int k = 0; k < 4; ++k) { if (idx+k < nb) s[idx+k] = run; run += v[k]; }
    if (t == 0) carry = c + ctot;
    __syncthreads();
  }
}

// ---------------- u64 packed scan (gt in lo32, tie in hi32) ----------------
__global__ void scan64_src(const u32* __restrict__ ymap, const u32* __restrict__ scal,
                           u64* __restrict__ part, u64* __restrict__ sums) {
  __shared__ u64 lds[256];
  int t = threadIdx.x;
  int base = blockIdx.x*1024 + t*4;
  int E = (int)scal[S_E];
  u32 TU = scal[S_TU];
  u64 v[4]; u64 tot = 0;
  for (int k = 0; k < 4; ++k) {
    int e = base + k;
    u64 val = 0;
    if (e < E) {
      u32 u = ymap[e];
      if (u > TU) val = 1ull;
      else if (u == TU) val = 1ull << 32;
    }
    v[k] = val; tot += val;
  }
  lds[t] = tot; __syncthreads();
  for (int o = 1; o < 256; o <<= 1) {
    u64 x = (t >= o) ? lds[t-o] : 0ull; __syncthreads();
    lds[t] += x; __syncthreads();
  }
  u64 excl = lds[t] - tot;
  if (t == 255) sums[blockIdx.x] = lds[255];
  u64 run = excl;
  for (int k = 0; k < 4; ++k) { part[base+k] = run; run += v[k]; }
}

__global__ void scan64_sums(u64* __restrict__ s, int nb) {
  __shared__ u64 lds[256];
  int t = threadIdx.x;
  int idx = t*4;
  u64 v[4]; u64 tot = 0;
  for (int k = 0; k < 4; ++k) { v[k] = (idx+k < nb) ? s[idx+k] : 0ull; tot += v[k]; }
  lds[t] = tot; __syncthreads();
  for (int o = 1; o < 256; o <<= 1) {
    u64 x = (t >= o) ? lds[t-o] : 0ull; __syncthreads();
    lds[t] += x; __syncthreads();
  }
  u64 excl = lds[t] - tot;
  u64 run = excl;
  for (int k = 0; k < 4; ++k) { if (idx+k < nb) s[idx+k] = run; run += v[k]; }
}

// sel + selr from packed prefix: selected = gt || (tie && TIEpre < R);
// rank among selected = GTpre + min(TIEpre, R)
__global__ void k_sel2(const u32* __restrict__ ymap, const u64* __restrict__ part,
                       const u64* __restrict__ sums, const u32* __restrict__ scal,
                       u32* __restrict__ sel, u32* __restrict__ selr) {
  int e = blockIdx.x*256 + threadIdx.x;
  if (e >= EMAX) return;
  int E = (int)scal[S_E];
  u32 TU = scal[S_TU], R = scal[S_R];
  u64 pre = part[e] + sums[e>>10];
  u32 GTpre = (u32)pre, TIEpre = (u32)(pre >> 32);
  u32 v = 0;
  if (e < E) {
    u32 u = ymap[e];
    v = (u > TU) || (u == TU && TIEpre < R);
  }
  sel[e] = v ? 1u : 0u;
  selr[e] = GTpre + min(TIEpre, R);
}

// ---------------- radix sort over packed u64 (key in hi32), 8-bit LSD ----------------
__global__ void k_rhist(const u64* __restrict__ kp, u32* __restrict__ hist,
                        int shift, int nb) {
  __shared__ u32 h[256];
  int t = threadIdx.x;
  h[t] = 0; __syncthreads();
  int i = blockIdx.x*256 + t;
  if (i < K3F) atomicAdd(&h[((u32)(kp[i]>>32) >> shift) & 255u], 1u);
  __syncthreads();
  hist[(u32)t*nb + blockIdx.x] = h[t];
}

__global__ void k_rscat(const u64* __restrict__ kp, u64* __restrict__ okp,
                        const u32* __restrict__ hist, const u32* __restrict__ sums,
                        int shift, int nb) {
  __shared__ u64 ball[4][8];
  __shared__ u64 vmask[4];
  int t = threadIdx.x, w = t>>6, lane = t&63;
  int i = blockIdx.x*256 + t;
  bool valid = i < K3F;
  u64 v = valid ? kp[i] : 0ull;
  u32 d = ((u32)(v>>32) >> shift) & 255u;
  for (int bit = 0; bit < 8; ++bit) {
    u64 bm = __ballot(valid && ((d>>bit)&1u));
    if (lane == 0) ball[w][bit] = bm;
  }
  u64 vb = __ballot(valid ? 1 : 0);
  if (lane == 0) vmask[w] = vb;
  __syncthreads();
  if (valid) {
    u32 rank = 0;
    for (int ww = 0; ww < w; ++ww) {
      u64 m = vmask[ww];
      for (int bit = 0; bit < 8; ++bit) { u64 bb = ball[ww][bit]; m &= ((d>>bit)&1u) ? bb : ~bb; }
      rank += (u32)__popcll(m);
    }
    u64 m = vmask[w];
    for (int bit = 0; bit < 8; ++bit) { u64 bb = ball[w][bit]; m &= ((d>>bit)&1u) ? bb : ~bb; }
    rank += (u32)__popcll(m & ((1ull<<lane)-1ull));
    u32 h = d*(u32)nb + blockIdx.x;
    u32 pos = hist[h] + sums[h>>10] + rank;
    okp[pos] = v;       // single 8B scatter (was 2x 4B to separate arrays)
  }
}

// ---------------- pipeline kernels ----------------
// keys + payload pack + pass-0 histogram + weight pack + small zero-inits, fused
__global__ void k_keys(const int* __restrict__ face,
                       const float* __restrict__ W1s, const float* __restrict__ W1n,
                       const float* __restrict__ b1,
                       const float* __restrict__ W2s, const float* __restrict__ W2n,
                       float* __restrict__ pk,
                       u64* __restrict__ kp, u32* __restrict__ hist,
                       u32* __restrict__ tkh, u32* __restrict__ done) {
  __shared__ u32 h[256];
  int t = threadIdx.x;
  h[t] = 0;
  __syncthreads();
  if (blockIdx.x == 0) {
    tkh[t] = 0u;
    if (t < 16) done[t] = 0u;
    float* p = pk + t*12;
    p[0] = W1s[t]; p[1] = W1s[256+t]; p[2] = W1s[512+t];
    p[3] = W1n[t]; p[4] = W1n[256+t]; p[5] = W1n[512+t];
    p[6] = b1[t];
    p[7] = W2s[2*t]; p[8] = W2s[2*t+1];
    p[9] = W2n[2*t]; p[10] = W2n[2*t+1];
    p[11] = 0.0f;
  }
  int i = blockIdx.x*256 + t;
  if (i < K3F) {
    int s = i / FN, f = i - s*FN;
    int v0 = face[f*3 + s];
    int v1 = face[f*3 + (s == 2 ? 0 : s+1)];
    int a = min(v0, v1), b = max(v0, v1);
    u32 key = ((u32)a * (u32)VN + (u32)b) ^ 0x80000000u;  // biased int32-wrap key
    kp[i] = ((u64)key << 32) | (u32)i;                     // payload = orig index
    atomicAdd(&h[key & 255u], 1u);                         // pass-0 hist for free
  }
  __syncthreads();
  hist[(u32)t*NB1 + blockIdx.x] = h[t];
}

// unique segments + feid scatter + edge-node outputs + xe gather + tk init, fused
__global__ void k_uwrite(const u64* __restrict__ kp, const u32* __restrict__ rankp,
                         const u32* __restrict__ sums, const float* __restrict__ x,
                         u32* __restrict__ segoff, u32* __restrict__ feid,
                         float* __restrict__ xe, float* __restrict__ dout,
                         u32* __restrict__ scal, const int* __restrict__ divp) {
  int p = blockIdx.x*256 + threadIdx.x;
  if (p >= K3F) return;
  u64 v = kp[p];
  u32 cur = (u32)(v >> 32);
  u32 fl = (p == 0 || (u32)(kp[p-1] >> 32) != cur) ? 1u : 0u;
  u32 rk = rankp[p] + sums[p>>10];
  if (fl) {
    u32 e = rk;
    segoff[e] = (u32)p;
    // ennode (fused): decode key -> endpoints + xe
    int k = (int)(cur ^ 0x80000000u);
    long long kk = (long long)k;
    long long qq = (kk - (kk < 0 ? (long long)(VN-1) : 0ll)) / VN; // floor div
    int q = (int)qq;
    int r = (int)(kk - qq * VN);
    dout[2*e]   = (float)q;
    dout[2*e+1] = (float)r;
    u32 i0 = (u32)(q < 0 ? q + VN : q);  // numpy negative-index wrap
    u32 i1 = (u32)r;
    for (int c = 0; c < 3; ++c) xe[e*3+c] = 0.5f*(x[i0*3+c] + x[i1*3+c]);
  }
  u32 id = rk - 1u + fl;
  u32 i = (u32)v;
  u32 s = i / FN, f = i - s*FN;
  feid[f*3 + s] = id;
  if (p == K3F-1) {
    u32 E = rk + fl;
    u32 num = E / (u32)divp[0];
    scal[S_E] = E; scal[S_NUM] = num;
    segoff[E] = (u32)K3F;
    scal[S_PFX] = 0u; scal[S_KREM] = num;   // top-k init (fused)
  }
}

// Neighbor aggregation direct from key-sort segments (bit-exact reference order).
__device__ __forceinline__ void agg_neighbors(int e, u32 st, u32 en,
                                              const u64* __restrict__ kp,
                                              const u32* __restrict__ feid,
                                              const float* __restrict__ v, int stride,
                                              float* acc0, float* acc1, float* acc2) {
  const int sslot[6] = {0,1,1,2,2,0};
  const int dslot[6] = {1,0,2,1,0,2};
  float c0 = 0.f, c1 = 0.f, c2 = 0.f;
  for (int b = 0; b < 6; ++b) {
    int j = dslot[b], isl = sslot[b];
    for (u32 p = st; p < en; ++p) {
      u32 i = (u32)kp[p];
      u32 s = i / FN;
      if ((int)s == j) {
        u32 f = i - s*FN;
        u32 u = feid[f*3 + isl];
        c0 += v[u*stride]; c1 += v[u*stride+1]; if (stride == 3) c2 += v[u*stride+2];
      }
    }
  }
  c0 += v[e*stride]; c1 += v[e*stride+1]; if (stride == 3) c2 += v[e*stride+2];
  *acc0 = c0; *acc1 = c1; *acc2 = c2;
}

// fused neighbor-mean + layer1(relu-gsnconv) + projection, thread-per-edge.
__global__ void k_l12(const float* __restrict__ xe, const u32* __restrict__ segoff,
                      const u64* __restrict__ kp, const u32* __restrict__ feid,
                      const u32* __restrict__ scal, const float* __restrict__ pk,
                      float* __restrict__ P, float* __restrict__ Q) {
  int e = blockIdx.x*256 + threadIdx.x;
  if (e >= (int)scal[S_E]) return;
  u32 st = segoff[e], en = segoff[e+1];
  float c0, c1, c2;
  agg_neighbors(e, st, en, kp, feid, xe, 3, &c0, &c1, &c2);
  float x0 = xe[e*3], x1 = xe[e*3+1], x2 = xe[e*3+2];
  float dg = (float)(2u*(en - st) + 1u);
  float m0 = c0/dg, m1 = c1/dg, m2 = c2/dg;
  float p0 = 0.f, p1 = 0.f, q0 = 0.f, q1 = 0.f;
#pragma unroll 8
  for (int hh = 0; hh < 256; ++hh) {
    const float* w = pk + hh*12;
    float s1 = x0*w[0] + x1*w[1] + x2*w[2];
    float s2 = m0*w[3] + m1*w[4] + m2*w[5];
    float h = fmaxf(s1 + s2 + w[6], 0.0f);
    p0 += h*w[7];  p1 += h*w[8];
    q0 += h*w[9];  q1 += h*w[10];
  }
  P[2*e] = p0; P[2*e+1] = p1; Q[2*e] = q0; Q[2*e+1] = q1;
}

__global__ void k_scores(const float* __restrict__ P, const float* __restrict__ Q,
                         const u32* __restrict__ segoff, const u64* __restrict__ kp,
                         const u32* __restrict__ feid,
                         const float* __restrict__ b2, const u32* __restrict__ scal,
                         float* __restrict__ Y, u32* __restrict__ ymap) {
  int e = blockIdx.x*256 + threadIdx.x;
  u32 E = scal[S_E];
  if (e >= (int)E) return;
  u32 st = segoff[e], en = segoff[e+1];
  float a0, a1, dummy;
  agg_neighbors(e, st, en, kp, feid, Q, 2, &a0, &a1, &dummy);
  float dg = (float)(2u*(en - st) + 1u);
  float z0 = P[2*e]   + a0/dg + b2[0];
  float z1 = P[2*e+1] + a1/dg + b2[1];
  float l0 = 1.0f/(1.0f + expf(-z0));
  float l1 = 1.0f/(1.0f + expf(-z1));
  u32 g0b, g1b;
  { u32 o0,o1; tf2x32(0u, 2u*(u32)e,      o0, o1); g0b = o0 ^ o1; }
  { u32 o0,o1; tf2x32(0u, 2u*(u32)e + 1u, o0, o1); g1b = o0 ^ o1; }
  float U0 = __uint_as_float((g0b>>9) | 0x3f800000u) - 1.0f;
  float U1 = __uint_as_float((g1b>>9) | 0x3f800000u) - 1.0f;
  float g0 = -logf(-logf(U0 + 1e-20f) + 1e-20f);
  float g1 = -logf(-logf(U1 + 1e-20f) + 1e-20f);
  float A0 = (l0 + g0)/0.1f;
  float A1 = (l1 + g1)/0.1f;
  float mx = fmaxf(A0, A1);
  float e0 = expf(A0-mx), e1 = expf(A1-mx);
  float y = e0/(e0+e1);
  Y[e] = y;
  ymap[e] = __float_as_uint(y) | 0x80000000u;
}

// ---------------- exact top-k: fused histogram + last-block select ----------------
__global__ void k_tkround(const u32* __restrict__ ymap, u32* __restrict__ scal,
                          u32* __restrict__ hist, u32* __restrict__ done, int byte) {
  __shared__ u32 h[256];
  __shared__ u32 s2[256];
  __shared__ u32 chosen_s;
  __shared__ u32 lastflag;
  int t = threadIdx.x;
  h[t] = 0u;
  if (t == 0) lastflag = 0u;
  __syncthreads();
  int E = (int)scal[S_E];
  u32 pfx = scal[S_PFX];
  int base = blockIdx.x*1024;
  for (int k = 0; k < 4; ++k) {
    int e = base + k*256 + t;
    if (e < E) {
      u32 u = ymap[e];
      bool match = (byte == 3) || ((u >> ((byte+1)*8)) == pfx);
      if (match) atomicAdd(&h[(u >> (byte*8)) & 255u], 1u);
    }
  }
  __syncthreads();
  u32 c = h[t];
  if (c) atomicAdd(&hist[t], c);
  __syncthreads();
  if (t == 0) {
    __threadfence();
    u32 old = atomicAdd(&done[byte], 1u);
    if (old == gridDim.x - 1u) lastflag = 1u;
  }
  __syncthreads();
  if (!lastflag) return;
  // last block: atomically read+zero hist, suffix-scan, pick bucket
  __threadfence();
  u32 v = atomicExch(&hist[t], 0u);
  s2[t] = v;
  if (t == 0) chosen_s = 0u;
  __syncthreads();
  for (int o = 1; o < 256; o <<= 1) {
    u32 x = (t + o < 256) ? s2[t+o] : 0u; __syncthreads();
    s2[t] += x; __syncthreads();
  }
  u32 krem = scal[S_KREM];
  if (s2[t] >= krem) atomicMax(&chosen_s, (u32)t);
  __syncthreads();
  if (t == 0) {
    u32 chosen = chosen_s;
    u32 sufnext = (chosen < 255u) ? s2[chosen+1] : 0u;
    u32 newkrem = krem - sufnext;
    u32 npfx = (scal[S_PFX] << 8) | chosen;
    scal[S_PFX] = npfx; scal[S_KREM] = newkrem;
    if (byte == 0) { scal[S_TU] = npfx; scal[S_R] = newkrem; }
  }
}

// ---------------- mesh collapse ----------------
// cat + per-block category histogram, fused
__global__ void k_catfused(const u32* __restrict__ feid, const u32* __restrict__ sel,
                           u32* __restrict__ cat, u32* __restrict__ ch) {
  __shared__ u32 h[8];
  int t = threadIdx.x;
  if (t < 8) h[t] = 0u;
  __syncthreads();
  int base = blockIdx.x*1024 + t*4;
  for (int k = 0; k < 4; ++k) {
    int f = base + k;
    if (f < FN) {
      u32 m0 = sel[feid[f*3]], m1 = sel[feid[f*3+1]], m2 = sel[feid[f*3+2]];
      u32 pen = m0 + m1 + m2;
      u32 psi = m1 + 2u*m2;
      u32 c = (pen == 0) ? 0u : (pen == 1) ? (1u+psi) : (pen == 2) ? (3u+psi) : 7u;
      cat[f] = c;
      atomicAdd(&h[c], 1u);
    }
  }
  __syncthreads();
  if (t < 8) ch[(u32)t*NBC + blockIdx.x] = h[t];
}

__global__ void k_catoff(u32* __restrict__ ch, u32* __restrict__ scal) {
  __shared__ u32 lds[256];
  __shared__ u32 ex[1024];
  int t = threadIdx.x;
  u32 v[4]; u32 tot = 0;
  for (int k = 0; k < 4; ++k) {
    int i = t*4 + k;
    u32 x = (i < 8*NBC) ? ch[i] : 0u;
    v[k] = x; tot += x;
  }
  lds[t] = tot; __syncthreads();
  for (int o = 1; o < 256; o <<= 1) {
    u32 x = (t >= o) ? lds[t-o] : 0u; __syncthreads();
    lds[t] += x; __syncthreads();
  }
  u32 excl = lds[t] - tot;
  u32 run = excl;
  for (int k = 0; k < 4; ++k) { ex[t*4+k] = run; run += v[k]; }
  __syncthreads();
  for (int k = 0; k < 4; ++k) {
    int i = t*4 + k;
    if (i < 8*NBC) ch[i] = ex[i];
  }
  if (t == 0) {
    u32 total = lds[255];
    u32 bnd[9];
    for (int c = 0; c < 8; ++c) bnd[c] = ex[c*NBC];
    bnd[8] = total;
    u32 tot8[8];
    for (int c = 0; c < 8; ++c) tot8[c] = bnd[c+1] - bnd[c];
    u32 n0 = tot8[0], n1 = tot8[1]+tot8[2]+tot8[3], n2 = tot8[4]+tot8[5]+tot8[6], n3 = tot8[7];
    u32 NF = n0 + 2u*n1 + 3u*n2 + 4u*n3;
    u32 E = scal[S_E], num = scal[S_NUM];
    u32 NEn = (u32)VN + num + 3u*NF;
    scal[S_NF] = NF; scal[S_NEN] = NEn;
    scal[S_O1] = 2u*E;
    scal[S_O2] = 2u*E + 3u*NF;
    scal[S_O3] = 2u*E + 3u*NF + 2u*NEn;
    u32 RS[8] = {0u, n0,n0,n0, n0+2u*n1, n0+2u*n1, n0+2u*n1, n0+2u*n1+3u*n2};
    u32 GS[8] = {0u, n1,n1,n1, n2,n2,n2, n3};
    u32 GP[8] = {0u, n0,n0,n0, n0+n1, n0+n1, n0+n1, n0+n1+n2};
    for (int i = 0; i < 8; ++i) { scal[S_RS+i] = RS[i]; scal[S_GS+i] = GS[i]; scal[S_GP+i] = GP[i]; }
  }
}

__global__ void k_catrank(const u32* __restrict__ cat, const u32* __restrict__ ch,
                          u32* __restrict__ cr) {
  __shared__ u32 lds[256];
  int t = threadIdx.x;
  int base = blockIdx.x*1024 + t*4;
  u32 cc[4], loc[4];
  u32 cnt[8] = {0,0,0,0,0,0,0,0};
  for (int k = 0; k < 4; ++k) {
    int i = base + k;
    if (i < FN) { u32 c = cat[i]; cc[k] = c; loc[k] = cnt[c]++; }
    else cc[k] = 8u;
  }
  u32 tb[8];
  for (int c = 0; c < 8; ++c) {
    lds[t] = cnt[c]; __syncthreads();
    for (int o = 1; o < 256; o <<= 1) {
      u32 x = (t >= o) ? lds[t-o] : 0u; __syncthreads();
      lds[t] += x; __syncthreads();
    }
    tb[c] = lds[t] - cnt[c];
    __syncthreads();
  }
  for (int k = 0; k < 4; ++k) {
    int i = base + k;
    if (i < FN) { u32 c = cc[k]; cr[i] = ch[c*NBC + blockIdx.x] + tb[c] + loc[k]; }
  }
}

__global__ void k_wfaces(const int* __restrict__ face, const u32* __restrict__ cat,
                         const u32* __restrict__ cr, const u32* __restrict__ feid,
                         const u32* __restrict__ selr, const u32* __restrict__ scal,
                         int* __restrict__ nfi, float* __restrict__ dout) {
  int f = blockIdx.x*256 + threadIdx.x;
  if (f >= FN) return;
  const int nfc[8] = {1,2,2,2,3,3,3,4};
  const int tri[8][4][3] = {
    {{0,2,4},{0,0,0},{0,0,0},{0,0,0}},
    {{0,1,4},{1,2,4},{0,0,0},{0,0,0}},
    {{2,3,0},{3,4,0},{0,0,0},{0,0,0}},
    {{4,5,2},{5,0,2},{0,0,0},{0,0,0}},
    {{0,1,4},{1,2,3},{1,3,4},{0,0,0}},
    {{4,5,2},{5,0,1},{5,1,2},{0,0,0}},
    {{2,3,0},{3,4,5},{3,5,0},{0,0,0}},
    {{0,1,5},{1,2,3},{1,3,5},{3,4,5}}};
  u32 c = cat[f];
  int cv[6];
  cv[0] = face[f*3];   cv[2] = face[f*3+1]; cv[4] = face[f*3+2];
  cv[1] = VN + (int)selr[feid[f*3]];
  cv[3] = VN + (int)selr[feid[f*3+1]];
  cv[5] = VN + (int)selr[feid[f*3+2]];
  u32 g  = cr[f] - scal[S_GP + c];
  u32 o1 = scal[S_O1];
  for (int j = 0; j < nfc[c]; ++j) {
    u32 row = scal[S_RS + c] + (u32)j*scal[S_GS + c] + g;
    for (int m = 0; m < 3; ++m) {
      int v = cv[tri[c][j][m]];
      nfi[row*3 + m] = v;
      dout[o1 + row*3 + m] = (float)v;
    }
  }
}

__global__ void k_wne(const int* __restrict__ nfi, const u32* __restrict__ scal,
                      float* __restrict__ dout) {
  int i = blockIdx.x*256 + threadIdx.x;
  u32 NEn = scal[S_NEN];
  if (i >= (int)NEn) return;
  u32 NF = scal[S_NF];
  u32 Vp = (u32)VN + scal[S_NUM];
  u32 o2 = scal[S_O2];
  int a, b;
  if ((u32)i < Vp) { a = i; b = i; }
  else {
    u32 j = (u32)i - Vp;
    u32 blk = j / NF, r = j - blk*NF;
    int i0 = (blk == 0) ? 0 : (blk == 1) ? 1 : 2;
    int i1 = (blk == 0) ? 1 : (blk == 1) ? 2 : 0;
    a = nfi[r*3 + i0]; b = nfi[r*3 + i1];
  }
  dout[o2 + i] = (float)a;
  dout[o2 + NEn + i] = (float)b;
}

__global__ void k_wmask(const u32* __restrict__ sel, const float* __restrict__ Y,
                        const u32* __restrict__ scal, float* __restrict__ dout) {
  int e = blockIdx.x*256 + threadIdx.x;
  if (e >= (int)scal[S_E]) return;
  float y = Y[e];
  float yh = sel[e] ? 1.0f : 0.0f;
  dout[scal[S_O3] + e] = (yh - y) + y;
}

// ---------------- host-side drivers ----------------
static void radix_pass(u32* hist, u32* sums, u64* kin, u64* kout, int shift,
                       bool do_hist, hipStream_t st) {
  if (do_hist) k_rhist<<<NB1, 256, 0, st>>>(kin, hist, shift, NB1);
  scan_blocks<<<NBS, 256, 0, st>>>(hist, hist, sums, NB1*256);
  scan_sums<<<1, 256, 0, st>>>(sums, NBS);
  k_rscat<<<NB1, 256, 0, st>>>(kin, kout, hist, sums, shift, NB1);
}

extern "C" void kernel_launch(void* const* d_in, const int* in_sizes, int n_in,
                              void* d_out, int out_size, void* d_ws, size_t ws_size,
                              hipStream_t stream) {
  const float* x    = (const float*)d_in[0];
  const int*   face = (const int*)d_in[1];
  const int*   divp = (const int*)d_in[4];
  const float* W1s  = (const float*)d_in[5];
  const float* W1n  = (const float*)d_in[6];
  const float* b1   = (const float*)d_in[7];
  const float* W2s  = (const float*)d_in[8];
  const float* W2n  = (const float*)d_in[9];
  const float* b2   = (const float*)d_in[10];
  float* out = (float*)d_out;
  u32* W = (u32*)d_ws;

  u64 *KPA = (u64*)(W+W_KPA), *KPB = (u64*)(W+W_KPB);
  u32 *RK = W+W_RANKU;
  u32 *HIST = W+W_HIST, *SUMS = W+W_SUMS, *SCAL = W+W_SCAL;
  u32 *TKH = W+W_TKH, *DONE = W+W_DONE;
  u64 *T64 = (u64*)(W+W_T64);
  u64 *SUMS64 = (u64*)(W+W_SUMS);

  // 1) keys (+pack +pass0 hist +inits), 4-pass u64 radix, unique(+ennode fused)
  k_keys<<<NB1, 256, 0, stream>>>(face, W1s, W1n, b1, W2s, W2n, (float*)(W+W_PK),
                                  KPA, HIST, TKH, DONE);
  radix_pass(HIST, SUMS, KPA, KPB,  0, false, stream);  // hist from k_keys
  radix_pass(HIST, SUMS, KPB, KPA,  8, true,  stream);
  radix_pass(HIST, SUMS, KPA, KPB, 16, true,  stream);
  radix_pass(HIST, SUMS, KPB, KPA, 24, true,  stream);
  scan_flagblocks<<<NBS, 256, 0, stream>>>(KPA, RK, SUMS, K3F);
  scan_sums<<<1, 256, 0, stream>>>(SUMS, NBS);
  k_uwrite<<<NB1, 256, 0, stream>>>(KPA, RK, SUMS, x, W+W_SEGOFF, W+W_FEID,
                                    (float*)(W+W_XE), out, SCAL, divp);

  // 2) GSN conv layers — neighbor aggregation direct from sort segments
  k_l12<<<NB1, 256, 0, stream>>>((float*)(W+W_XE), W+W_SEGOFF, KPA, W+W_FEID, SCAL,
                                 (float*)(W+W_PK), (float*)(W+W_P), (float*)(W+W_Q));
  k_scores<<<NB1, 256, 0, stream>>>((float*)(W+W_P), (float*)(W+W_Q), W+W_SEGOFF, KPA,
                                    W+W_FEID, b2, SCAL, (float*)(W+W_Y), W+W_YMAP);

  // 3) exact top-k (fused hist+select per byte) + packed u64 scan for sel/selr
  for (int byte = 3; byte >= 0; --byte)
    k_tkround<<<NBH, 256, 0, stream>>>(W+W_YMAP, SCAL, TKH, DONE, byte);
  scan64_src<<<NBS, 256, 0, stream>>>(W+W_YMAP, SCAL, T64, SUMS64);
  scan64_sums<<<1, 256, 0, stream>>>(SUMS64, NBS);
  k_sel2<<<NB1, 256, 0, stream>>>(W+W_YMAP, T64, SUMS64, SCAL, W+W_SEL, W+W_SELR);

  // 4) mesh collapse
  k_catfused<<<NBC, 256, 0, stream>>>(W+W_FEID, W+W_SEL, W+W_CAT, W+W_CATH);
  k_catoff<<<1, 256, 0, stream>>>(W+W_CATH, SCAL);
  k_catrank<<<NBC, 256, 0, stream>>>(W+W_CAT, W+W_CATH, W+W_CATR);
  k_wfaces<<<391, 256, 0, stream>>>(face, W+W_CAT, W+W_CATR, W+W_FEID, W+W_SELR, SCAL,
                                    (int*)(W+W_NFI), out);
  k_wne<<<5118, 256, 0, stream>>>((int*)(W+W_NFI), SCAL, out);
  k_wmask<<<NB1, 256, 0, stream>>>(W+W_SEL, (float*)(W+W_Y), SCAL, out);
}